// Round 1
// baseline (1579.927 us; speedup 1.0000x reference)
//
#include <hip/hip_runtime.h>
#include <math.h>

#define B_    4
#define SEQ_  2048
#define S_    128
#define L_    2304          // SEQ + 2*S
#define DIN   512
#define DK    64
#define DV    64
#define NEGINF (-1e30f)
#define SCALE 0.125f        // 1/sqrt(64)

// ---------------------------------------------------------------------------
// Kernel 1: fused LayerNorm + QKV projection. One block per row (B*L rows).
// Writes q_full / k_full / v_full, each (B, L, 64) fp32, into workspace.
// ---------------------------------------------------------------------------
__global__ __launch_bounds__(256) void k_lnproj(
    const float* __restrict__ x,
    const float* __restrict__ Wq,  const float* __restrict__ Wk,  const float* __restrict__ Wv,
    const float* __restrict__ Wqs, const float* __restrict__ Wks, const float* __restrict__ Wvs,
    const float* __restrict__ Wqe, const float* __restrict__ Wke, const float* __restrict__ Wve,
    const float* __restrict__ g0, const float* __restrict__ b0,
    const float* __restrict__ gs, const float* __restrict__ bs,
    const float* __restrict__ ge, const float* __restrict__ be,
    float* __restrict__ qf, float* __restrict__ kf, float* __restrict__ vf)
{
    __shared__ float xn[DIN];
    __shared__ float red[256];
    const int row = blockIdx.x;          // global row in [0, B*L)
    const int r   = row % L_;            // position within sequence
    const int tid = threadIdx.x;

    const float* xr = x + (size_t)row * DIN;
    float x0 = xr[tid], x1 = xr[tid + 256];

    // mean
    red[tid] = x0 + x1;
    __syncthreads();
    for (int off = 128; off > 0; off >>= 1) {
        if (tid < off) red[tid] += red[tid + off];
        __syncthreads();
    }
    float mean = red[0] / (float)DIN;
    __syncthreads();
    // var (E[x^2] - mean^2)
    red[tid] = x0 * x0 + x1 * x1;
    __syncthreads();
    for (int off = 128; off > 0; off >>= 1) {
        if (tid < off) red[tid] += red[tid + off];
        __syncthreads();
    }
    float var  = red[0] / (float)DIN - mean * mean;
    float rstd = rsqrtf(var + 1e-5f);

    const float *gg, *bb, *wq, *wk, *wv;
    if (r < S_)            { gg = gs; bb = bs; wq = Wqs; wk = Wks; wv = Wvs; }
    else if (r >= L_ - S_) { gg = ge; bb = be; wq = Wqe; wk = Wke; wv = Wve; }
    else                   { gg = g0; bb = b0; wq = Wq;  wk = Wk;  wv = Wv;  }

    xn[tid]       = (x0 - mean) * rstd * gg[tid]       + bb[tid];
    xn[tid + 256] = (x1 - mean) * rstd * gg[tid + 256] + bb[tid + 256];
    __syncthreads();

    if (tid < 192) {
        const int w = tid >> 6, d = tid & 63;
        const float* W = (w == 0) ? wq : (w == 1) ? wk : wv;
        float acc = 0.f;
        #pragma unroll 8
        for (int i = 0; i < DIN; ++i) acc += xn[i] * W[i * DK + d];
        float* o = (w == 0) ? qf : (w == 1) ? kf : vf;
        o[(size_t)row * DK + d] = acc;
    }
}

// ---------------------------------------------------------------------------
// Kernel 2: middle rows (B*2048 blocks). Per row:
//   dots to all 2048 middle keys -> sigmoid gates -> suffix scan (CoPE pos)
//   -> interpolated bias -> causal-masked softmax over {start keys, mid keys}
//   -> PV accumulation.
// ---------------------------------------------------------------------------
__global__ __launch_bounds__(256) void k_attn_mid(
    const float* __restrict__ qf, const float* __restrict__ kf,
    const float* __restrict__ vf, const float* __restrict__ cope,
    float* __restrict__ out)
{
    __shared__ float qv[DK];
    __shared__ float li[S_];     // cope logits for this q row
    __shared__ float sc[SEQ_];   // mid-key probs
    __shared__ float sb[S_];     // start-key probs
    __shared__ float red[256];

    const int blk = blockIdx.x;
    const int b   = blk / SEQ_;
    const int q   = blk % SEQ_;           // middle-local row index
    const int tid = threadIdx.x;
    const size_t base = (size_t)b * L_ * DK;

    if (tid < DK) qv[tid] = qf[base + (size_t)(S_ + q) * DK + tid];
    __syncthreads();

    // cope logits: li[t] = q . cope[:, t]
    if (tid < S_) {
        float acc = 0.f;
        #pragma unroll
        for (int d = 0; d < DK; ++d) acc += qv[d] * cope[d * S_ + tid];
        li[tid] = acc;
    }

    // dots to mid keys: 8 contiguous keys per thread, q float4 reused x8
    const float4* k4  = (const float4*)(kf + base + (size_t)S_ * DK);
    const float4* q4s = (const float4*)qv;
    const int j0 = tid * 8;
    float dot[8];
    #pragma unroll
    for (int jj = 0; jj < 8; ++jj) dot[jj] = 0.f;
    #pragma unroll
    for (int dd = 0; dd < 16; ++dd) {
        float4 qq = q4s[dd];
        #pragma unroll
        for (int jj = 0; jj < 8; ++jj) {
            float4 kk = k4[(size_t)(j0 + jj) * 16 + dd];
            dot[jj] += qq.x * kk.x + qq.y * kk.y + qq.z * kk.z + qq.w * kk.w;
        }
    }

    // gates + per-thread chunk sum
    float gte[8];
    float csum = 0.f;
    #pragma unroll
    for (int jj = 0; jj < 8; ++jj) {
        gte[jj] = 1.f / (1.f + expf(-dot[jj]));
        csum += gte[jj];
    }

    // inclusive suffix scan of 256 chunk sums (Hillis-Steele)
    red[tid] = csum;
    __syncthreads();
    for (int off = 1; off < 256; off <<= 1) {
        float v = red[tid] + ((tid + off < 256) ? red[tid + off] : 0.f);
        __syncthreads();
        red[tid] = v;
        __syncthreads();
    }
    float run = (tid < 255) ? red[tid + 1] : 0.f;  // sum of chunks to the right

    // within-chunk suffix, CoPE interpolation, masked score
    float p[8];
    #pragma unroll
    for (int jj = 7; jj >= 0; --jj) {
        run += gte[jj];
        float pos = fminf(run, (float)(S_ - 1));
        float pfl = floorf(pos);
        int   ic  = (int)ceilf(pos);
        int   ifl = (int)pfl;
        float w   = pos - pfl;
        float bias = li[ic] * w + li[ifl] * (1.f - w);
        int j = j0 + jj;
        p[jj] = (j <= q) ? (dot[jj] * SCALE + bias) : NEGINF;
    }

    // start-segment scores (always causal-visible from middle rows)
    if (tid < S_) {
        const float* kr = kf + base + (size_t)tid * DK;
        float acc = 0.f;
        #pragma unroll
        for (int d = 0; d < DK; ++d) acc += qv[d] * kr[d];
        sb[tid] = acc * SCALE;
    }

    // block max
    float mx = NEGINF;
    #pragma unroll
    for (int jj = 0; jj < 8; ++jj) mx = fmaxf(mx, p[jj]);
    if (tid < S_) mx = fmaxf(mx, sb[tid]);
    red[tid] = mx;
    __syncthreads();
    for (int off = 128; off > 0; off >>= 1) {
        if (tid < off) red[tid] = fmaxf(red[tid], red[tid + off]);
        __syncthreads();
    }
    mx = red[0];
    __syncthreads();

    // exp + sum
    float lsum = 0.f;
    #pragma unroll
    for (int jj = 0; jj < 8; ++jj) {
        float e = expf(p[jj] - mx);
        sc[j0 + jj] = e;
        lsum += e;
    }
    if (tid < S_) {
        float e = expf(sb[tid] - mx);
        sb[tid] = e;
        lsum += e;
    }
    red[tid] = lsum;
    __syncthreads();
    for (int off = 128; off > 0; off >>= 1) {
        if (tid < off) red[tid] += red[tid + off];
        __syncthreads();
    }
    float denom = red[0];
    __syncthreads();

    // PV: 4 groups x 64 dims
    const int d = tid & 63, grp = tid >> 6;
    float acc = 0.f;
    const float* vs = vf + base;
    for (int t = grp; t < S_; t += 4) acc += sb[t] * vs[(size_t)t * DK + d];
    const float* vm = vf + base + (size_t)S_ * DK;
    for (int j = grp; j <= q; j += 4) acc += sc[j] * vm[(size_t)j * DK + d];
    red[tid] = acc;
    __syncthreads();
    if (tid < 64) {
        float o = red[tid] + red[tid + 64] + red[tid + 128] + red[tid + 192];
        out[((size_t)b * L_ + S_ + q) * DK + tid] = o / denom;
    }
}

// ---------------------------------------------------------------------------
// Kernel 3: edge rows (start + end), plain causal attention over contiguous
// k_full/v_full rows 0..Q, no CoPE bias. B*2*S blocks.
// ---------------------------------------------------------------------------
__global__ __launch_bounds__(256) void k_attn_edge(
    const float* __restrict__ qf, const float* __restrict__ kf,
    const float* __restrict__ vf, float* __restrict__ out)
{
    __shared__ float qv[DK];
    __shared__ float sc[L_];     // 2304 probs
    __shared__ float red[256];

    const int blk = blockIdx.x;
    const int b   = blk / (2 * S_);
    const int r   = blk % (2 * S_);
    const int Q   = (r < S_) ? r : (L_ - S_ + (r - S_));   // global row index
    const int tid = threadIdx.x;
    const size_t base = (size_t)b * L_ * DK;

    if (tid < DK) qv[tid] = qf[base + (size_t)Q * DK + tid];
    __syncthreads();

    const int CH = 9;                    // ceil(2304/256)
    const int j0 = tid * CH;
    float p[CH];
    #pragma unroll
    for (int jj = 0; jj < CH; ++jj) p[jj] = 0.f;

    const float4* q4s = (const float4*)qv;
    const float4* k4  = (const float4*)(kf + base);
    #pragma unroll
    for (int dd = 0; dd < 16; ++dd) {
        float4 qq = q4s[dd];
        #pragma unroll
        for (int jj = 0; jj < CH; ++jj) {
            float4 kk = k4[(size_t)(j0 + jj) * 16 + dd];
            p[jj] += qq.x * kk.x + qq.y * kk.y + qq.z * kk.z + qq.w * kk.w;
        }
    }

    float mx = NEGINF;
    #pragma unroll
    for (int jj = 0; jj < CH; ++jj) {
        int j = j0 + jj;
        p[jj] = (j <= Q) ? p[jj] * SCALE : NEGINF;
        mx = fmaxf(mx, p[jj]);
    }
    red[tid] = mx;
    __syncthreads();
    for (int off = 128; off > 0; off >>= 1) {
        if (tid < off) red[tid] = fmaxf(red[tid], red[tid + off]);
        __syncthreads();
    }
    mx = red[0];
    __syncthreads();

    float lsum = 0.f;
    #pragma unroll
    for (int jj = 0; jj < CH; ++jj) {
        float e = expf(p[jj] - mx);
        sc[j0 + jj] = e;
        lsum += e;
    }
    red[tid] = lsum;
    __syncthreads();
    for (int off = 128; off > 0; off >>= 1) {
        if (tid < off) red[tid] += red[tid + off];
        __syncthreads();
    }
    float denom = red[0];
    __syncthreads();

    const int d = tid & 63, grp = tid >> 6;
    float acc = 0.f;
    const float* vr = vf + base;
    for (int j = grp; j <= Q; j += 4) acc += sc[j] * vr[(size_t)j * DK + d];
    red[tid] = acc;
    __syncthreads();
    if (tid < 64) {
        float o = red[tid] + red[tid + 64] + red[tid + 128] + red[tid + 192];
        out[((size_t)b * L_ + Q) * DK + tid] = o / denom;
    }
}

// ---------------------------------------------------------------------------
extern "C" void kernel_launch(void* const* d_in, const int* in_sizes, int n_in,
                              void* d_out, int out_size, void* d_ws, size_t ws_size,
                              hipStream_t stream)
{
    const float* x    = (const float*)d_in[0];
    const float* Wq   = (const float*)d_in[1];
    const float* Wk   = (const float*)d_in[2];
    const float* Wv   = (const float*)d_in[3];
    const float* Wqs  = (const float*)d_in[4];
    const float* Wks  = (const float*)d_in[5];
    const float* Wvs  = (const float*)d_in[6];
    const float* Wqe  = (const float*)d_in[7];
    const float* Wke  = (const float*)d_in[8];
    const float* Wve  = (const float*)d_in[9];
    const float* g0   = (const float*)d_in[10];
    const float* b0   = (const float*)d_in[11];
    const float* gs   = (const float*)d_in[12];
    const float* bs   = (const float*)d_in[13];
    const float* ge   = (const float*)d_in[14];
    const float* be   = (const float*)d_in[15];
    const float* cope = (const float*)d_in[16];
    // d_in[17] = offset, unused by the reference math

    float* qf = (float*)d_ws;
    float* kf = qf + (size_t)B_ * L_ * DK;
    float* vf = kf + (size_t)B_ * L_ * DK;
    float* out = (float*)d_out;

    k_lnproj<<<B_ * L_, 256, 0, stream>>>(x,
        Wq, Wk, Wv, Wqs, Wks, Wvs, Wqe, Wke, Wve,
        g0, b0, gs, bs, ge, be, qf, kf, vf);
    k_attn_mid<<<B_ * SEQ_, 256, 0, stream>>>(qf, kf, vf, cope, out);
    k_attn_edge<<<B_ * 2 * S_, 256, 0, stream>>>(qf, kf, vf, out);
}

// Round 2
// 669.125 us; speedup vs baseline: 2.3612x; 2.3612x over previous
//
#include <hip/hip_runtime.h>
#include <math.h>

#define B_    4
#define SEQ_  2048
#define S_    128
#define L_    2304          // SEQ + 2*S
#define DIN   512
#define DK    64
#define DV    64
#define NEGINF (-1e30f)
#define SCALE 0.125f        // 1/sqrt(64)

#define QT    32            // q rows per mid block
#define TK    64            // key tile (mid)
#define TKE   128           // key tile (edge)
#define KST   68            // padded LDS row stride (floats)

// ---------------------------------------------------------------------------
// Kernel 1: fused LayerNorm + QKV projection. One block per row (B*L rows).
// ---------------------------------------------------------------------------
__global__ __launch_bounds__(256) void k_lnproj(
    const float* __restrict__ x,
    const float* __restrict__ Wq,  const float* __restrict__ Wk,  const float* __restrict__ Wv,
    const float* __restrict__ Wqs, const float* __restrict__ Wks, const float* __restrict__ Wvs,
    const float* __restrict__ Wqe, const float* __restrict__ Wke, const float* __restrict__ Wve,
    const float* __restrict__ g0, const float* __restrict__ b0,
    const float* __restrict__ gs, const float* __restrict__ bs,
    const float* __restrict__ ge, const float* __restrict__ be,
    float* __restrict__ qf, float* __restrict__ kf, float* __restrict__ vf)
{
    __shared__ float xn[DIN];
    __shared__ float red[256];
    const int row = blockIdx.x;
    const int r   = row % L_;
    const int tid = threadIdx.x;

    const float* xr = x + (size_t)row * DIN;
    float x0 = xr[tid], x1 = xr[tid + 256];

    red[tid] = x0 + x1;
    __syncthreads();
    for (int off = 128; off > 0; off >>= 1) {
        if (tid < off) red[tid] += red[tid + off];
        __syncthreads();
    }
    float mean = red[0] / (float)DIN;
    __syncthreads();
    red[tid] = x0 * x0 + x1 * x1;
    __syncthreads();
    for (int off = 128; off > 0; off >>= 1) {
        if (tid < off) red[tid] += red[tid + off];
        __syncthreads();
    }
    float var  = red[0] / (float)DIN - mean * mean;
    float rstd = rsqrtf(var + 1e-5f);

    const float *gg, *bb, *wq, *wk, *wv;
    if (r < S_)            { gg = gs; bb = bs; wq = Wqs; wk = Wks; wv = Wvs; }
    else if (r >= L_ - S_) { gg = ge; bb = be; wq = Wqe; wk = Wke; wv = Wve; }
    else                   { gg = g0; bb = b0; wq = Wq;  wk = Wk;  wv = Wv;  }

    xn[tid]       = (x0 - mean) * rstd * gg[tid]       + bb[tid];
    xn[tid + 256] = (x1 - mean) * rstd * gg[tid + 256] + bb[tid + 256];
    __syncthreads();

    if (tid < 192) {
        const int w = tid >> 6, d = tid & 63;
        const float* W = (w == 0) ? wq : (w == 1) ? wk : wv;
        float acc = 0.f;
        #pragma unroll 8
        for (int i = 0; i < DIN; ++i) acc += xn[i] * W[i * DK + d];
        float* o = (w == 0) ? qf : (w == 1) ? kf : vf;
        o[(size_t)row * DK + d] = acc;
    }
}

// --- helpers ---------------------------------------------------------------
__device__ __forceinline__ void stage64(const float* __restrict__ gsrc,
                                        float* __restrict__ dst, int tid)
{
    // stage 64 rows x 64 floats (row-major) into LDS rows of stride KST
    const float4* s4 = (const float4*)gsrc;
    #pragma unroll
    for (int i = 0; i < 4; ++i) {
        int g = tid + 256 * i;           // 0..1023
        int k = g >> 4, f = g & 15;
        *(float4*)(dst + k * KST + f * 4) = s4[g];
    }
}

__device__ __forceinline__ void dot8(const float* __restrict__ Qs,
                                     const float* __restrict__ Ks,
                                     int rg, int kg, float* d0, float* d1)
{
    #pragma unroll
    for (int i = 0; i < 4; ++i) { d0[i] = 0.f; d1[i] = 0.f; }
    #pragma unroll
    for (int dd = 0; dd < 16; ++dd) {
        float4 k0 = *(const float4*)(Ks + kg * KST + dd * 4);
        float4 k1 = *(const float4*)(Ks + (kg + 32) * KST + dd * 4);
        #pragma unroll
        for (int i = 0; i < 4; ++i) {
            float4 q = *(const float4*)(Qs + (rg * 4 + i) * KST + dd * 4);
            d0[i] += q.x * k0.x + q.y * k0.y + q.z * k0.z + q.w * k0.w;
            d1[i] += q.x * k1.x + q.y * k1.y + q.z * k1.z + q.w * k1.w;
        }
    }
}

// ---------------------------------------------------------------------------
// Kernel 2: middle rows, flash-style. Grid = B*64 blocks, 256 threads.
// Block handles 32 q-rows.  Two passes over mid keys:
//   pass 1: gate tile-sums (64-key tiles);  inter: per-row tile prefix scan;
//   pass 2: recompute dots, exact suffix = total - prefix, CoPE bias,
//           online softmax + PV.  Start keys = tiles t=-2,-1 (no bias).
// ---------------------------------------------------------------------------
__global__ __launch_bounds__(256) void k_attn_mid(
    const float* __restrict__ qf, const float* __restrict__ kf,
    const float* __restrict__ vf, const float* __restrict__ cope,
    float* __restrict__ out)
{
    __shared__ float Qs[QT * KST];
    __shared__ float Ks[TK * KST];
    __shared__ float Vs[TK * KST];
    __shared__ float Ds[QT * KST];
    __shared__ float Li[QT * 128];
    __shared__ float Ts[QT * 36];     // cols 0..31 tile prefix (excl), col 32 total

    const int tid = threadIdx.x;
    const int b   = blockIdx.x >> 6;
    const int q0  = (blockIdx.x & 63) * QT;
    const size_t base = (size_t)b * L_ * DK;

    // load Q tile
    {
        const float4* src = (const float4*)(qf + base + (size_t)(S_ + q0) * DK);
        #pragma unroll
        for (int i = 0; i < 2; ++i) {
            int g = tid + 256 * i;       // 0..511 (32 rows x 16 f4)
            int rr = g >> 4, f = g & 15;
            *(float4*)(Qs + rr * KST + f * 4) = src[g];
        }
    }
    __syncthreads();

    // cope logits Li[r][p] = Q[r] . cope[:,p]
    {
        int p = tid & 127, half = tid >> 7;
        float acc[16];
        #pragma unroll
        for (int i = 0; i < 16; ++i) acc[i] = 0.f;
        for (int d = 0; d < DK; ++d) {
            float cv = cope[d * S_ + p];
            #pragma unroll
            for (int i = 0; i < 16; ++i)
                acc[i] += Qs[(half * 16 + i) * KST + d] * cv;
        }
        #pragma unroll
        for (int i = 0; i < 16; ++i) Li[(half * 16 + i) * 128 + p] = acc[i];
    }

    const int rg = tid >> 5, kg = tid & 31;

    // ---- pass 1: gate tile sums over all 32 mid tiles
    for (int t = 0; t < SEQ_ / TK; ++t) {
        __syncthreads();
        stage64(kf + base + (size_t)(S_ + t * TK) * DK, Ks, tid);
        __syncthreads();
        float d0[4], d1[4];
        dot8(Qs, Ks, rg, kg, d0, d1);
        #pragma unroll
        for (int i = 0; i < 4; ++i) {
            float g = 1.f / (1.f + __expf(-d0[i])) + 1.f / (1.f + __expf(-d1[i]));
            #pragma unroll
            for (int m = 16; m >= 1; m >>= 1) g += __shfl_xor(g, m, 32);
            if (kg == 0) Ts[(rg * 4 + i) * 36 + t] = g;
        }
    }
    __syncthreads();
    // per-row exclusive tile prefix + total
    if (tid < QT) {
        float v[32];
        #pragma unroll
        for (int t8 = 0; t8 < 8; ++t8)
            *(float4*)&v[t8 * 4] = *(const float4*)(Ts + tid * 36 + t8 * 4);
        float run = 0.f;
        #pragma unroll
        for (int t = 0; t < 32; ++t) { float xx = v[t]; v[t] = run; run += xx; }
        #pragma unroll
        for (int t8 = 0; t8 < 8; ++t8)
            *(float4*)(Ts + tid * 36 + t8 * 4) = *(float4*)&v[t8 * 4];
        Ts[tid * 36 + 32] = run;
    }

    // ---- pass 2: online softmax + PV
    const int r_sc = tid >> 3, c_sc = tid & 7;
    const int q_sc = q0 + r_sc;
    float m_r = NEGINF, l_r = 0.f;
    float oacc[8];
    #pragma unroll
    for (int i = 0; i < 8; ++i) oacc[i] = 0.f;

    const int tmax = (q0 + QT - 1) / TK;
    for (int t = -2; t <= tmax; ++t) {
        __syncthreads();
        stage64(kf + base + (size_t)(S_ + t * TK) * DK, Ks, tid);
        stage64(vf + base + (size_t)(S_ + t * TK) * DK, Vs, tid);
        __syncthreads();
        float d0[4], d1[4];
        dot8(Qs, Ks, rg, kg, d0, d1);
        #pragma unroll
        for (int i = 0; i < 4; ++i) {
            Ds[(rg * 4 + i) * KST + kg]      = d0[i];
            Ds[(rg * 4 + i) * KST + kg + 32] = d1[i];
        }
        __syncthreads();

        float s8[8];
        *(float4*)&s8[0] = *(const float4*)(Ds + r_sc * KST + c_sc * 8);
        *(float4*)&s8[4] = *(const float4*)(Ds + r_sc * KST + c_sc * 8 + 4);

        if (t >= 0) {
            float g8[8], csum = 0.f;
            #pragma unroll
            for (int j = 0; j < 8; ++j) {
                g8[j] = 1.f / (1.f + __expf(-s8[j]));
                csum += g8[j];
            }
            float pre = csum;
            #pragma unroll
            for (int dlt = 1; dlt < 8; dlt <<= 1) {
                float u = __shfl_up(pre, dlt, 8);
                if (c_sc >= dlt) pre += u;
            }
            pre -= csum;   // exclusive chunk prefix
            float run = Ts[r_sc * 36 + t] + pre;
            float tot = Ts[r_sc * 36 + 32];
            #pragma unroll
            for (int j = 0; j < 8; ++j) {
                float suf = tot - run;       // inclusive suffix at this key
                run += g8[j];
                float pos = fminf(fmaxf(suf, 0.f), (float)(S_ - 1));
                int ifl = (int)pos;
                int ic  = (int)ceilf(pos);
                float w = pos - (float)ifl;
                float bias = Li[r_sc * 128 + ic] * w + Li[r_sc * 128 + ifl] * (1.f - w);
                int jm = t * TK + c_sc * 8 + j;
                s8[j] = (jm <= q_sc) ? s8[j] * SCALE + bias : NEGINF;
            }
        } else {
            #pragma unroll
            for (int j = 0; j < 8; ++j) s8[j] *= SCALE;
        }

        float mx = s8[0];
        #pragma unroll
        for (int j = 1; j < 8; ++j) mx = fmaxf(mx, s8[j]);
        #pragma unroll
        for (int mm = 1; mm < 8; mm <<= 1) mx = fmaxf(mx, __shfl_xor(mx, mm, 8));
        float mnew  = fmaxf(m_r, mx);
        float alpha = __expf(m_r - mnew);
        float esum = 0.f;
        #pragma unroll
        for (int j = 0; j < 8; ++j) {
            float e = __expf(s8[j] - mnew);
            s8[j] = e; esum += e;
        }
        #pragma unroll
        for (int mm = 1; mm < 8; mm <<= 1) esum += __shfl_xor(esum, mm, 8);
        l_r = l_r * alpha + esum;
        m_r = mnew;
        *(float4*)(Ds + r_sc * KST + c_sc * 8)     = *(float4*)&s8[0];
        *(float4*)(Ds + r_sc * KST + c_sc * 8 + 4) = *(float4*)&s8[4];
        #pragma unroll
        for (int i = 0; i < 8; ++i) oacc[i] *= alpha;
        __syncthreads();

        #pragma unroll 8
        for (int j = 0; j < TK; ++j) {
            float p  = Ds[r_sc * KST + j];
            float4 v0 = *(const float4*)(Vs + j * KST + c_sc * 8);
            float4 v1 = *(const float4*)(Vs + j * KST + c_sc * 8 + 4);
            oacc[0] += p * v0.x; oacc[1] += p * v0.y;
            oacc[2] += p * v0.z; oacc[3] += p * v0.w;
            oacc[4] += p * v1.x; oacc[5] += p * v1.y;
            oacc[6] += p * v1.z; oacc[7] += p * v1.w;
        }
    }

    float inv = 1.f / l_r;
    float4 o0 = make_float4(oacc[0]*inv, oacc[1]*inv, oacc[2]*inv, oacc[3]*inv);
    float4 o1 = make_float4(oacc[4]*inv, oacc[5]*inv, oacc[6]*inv, oacc[7]*inv);
    float* op = out + base + (size_t)(S_ + q0 + r_sc) * DK + c_sc * 8;
    *(float4*)op       = o0;
    *(float4*)(op + 4) = o1;
}

// ---------------------------------------------------------------------------
// Kernel 3: edge rows (start + end), causal over contiguous rows 0..Q,
// no CoPE bias. K staged through LDS in 128-key tiles. B*2*S blocks.
// ---------------------------------------------------------------------------
__global__ __launch_bounds__(256) void k_attn_edge(
    const float* __restrict__ qf, const float* __restrict__ kf,
    const float* __restrict__ vf, float* __restrict__ out)
{
    __shared__ float qv[DK];
    __shared__ float Ks[TKE * KST];
    __shared__ float sc[L_];
    __shared__ float red[256];

    const int blk = blockIdx.x;
    const int b   = blk / (2 * S_);
    const int r   = blk % (2 * S_);
    const int Q   = (r < S_) ? r : (L_ - S_ + (r - S_));
    const int tid = threadIdx.x;
    const size_t base = (size_t)b * L_ * DK;

    if (tid < DK) qv[tid] = qf[base + (size_t)Q * DK + tid];

    const int ntile = Q / TKE + 1;
    for (int t = 0; t < ntile; ++t) {
        __syncthreads();
        const float4* s4 = (const float4*)(kf + base + (size_t)t * TKE * DK);
        #pragma unroll
        for (int i = 0; i < 8; ++i) {
            int g = tid + 256 * i;       // 0..2047
            int k = g >> 4, f = g & 15;
            *(float4*)(Ks + k * KST + f * 4) = s4[g];
        }
        __syncthreads();
        if (tid < TKE) {
            float acc = 0.f;
            const float4* q4 = (const float4*)qv;
            #pragma unroll
            for (int dd = 0; dd < 16; ++dd) {
                float4 qq = q4[dd];
                float4 kk = *(const float4*)(Ks + tid * KST + dd * 4);
                acc += qq.x * kk.x + qq.y * kk.y + qq.z * kk.z + qq.w * kk.w;
            }
            int j = t * TKE + tid;
            sc[j] = (j <= Q) ? acc * SCALE : NEGINF;
        }
    }
    __syncthreads();
    for (int j = tid; j < L_; j += 256) if (j > Q) sc[j] = NEGINF;
    __syncthreads();

    const int j0 = tid * 9;
    float mx = NEGINF;
    #pragma unroll
    for (int jj = 0; jj < 9; ++jj) mx = fmaxf(mx, sc[j0 + jj]);
    red[tid] = mx;
    __syncthreads();
    for (int off = 128; off > 0; off >>= 1) {
        if (tid < off) red[tid] = fmaxf(red[tid], red[tid + off]);
        __syncthreads();
    }
    mx = red[0];
    __syncthreads();

    float lsum = 0.f;
    #pragma unroll
    for (int jj = 0; jj < 9; ++jj) {
        float e = __expf(sc[j0 + jj] - mx);
        sc[j0 + jj] = e;
        lsum += e;
    }
    red[tid] = lsum;
    __syncthreads();
    for (int off = 128; off > 0; off >>= 1) {
        if (tid < off) red[tid] += red[tid + off];
        __syncthreads();
    }
    float denom = red[0];
    __syncthreads();

    const int d = tid & 63, grp = tid >> 6;
    float acc = 0.f;
    const float* vr = vf + base;
    for (int j = grp; j <= Q; j += 4) acc += sc[j] * vr[(size_t)j * DK + d];
    red[tid] = acc;
    __syncthreads();
    if (tid < 64) {
        float o = red[tid] + red[tid + 64] + red[tid + 128] + red[tid + 192];
        out[((size_t)b * L_ + Q) * DK + tid] = o / denom;
    }
}

// ---------------------------------------------------------------------------
extern "C" void kernel_launch(void* const* d_in, const int* in_sizes, int n_in,
                              void* d_out, int out_size, void* d_ws, size_t ws_size,
                              hipStream_t stream)
{
    const float* x    = (const float*)d_in[0];
    const float* Wq   = (const float*)d_in[1];
    const float* Wk   = (const float*)d_in[2];
    const float* Wv   = (const float*)d_in[3];
    const float* Wqs  = (const float*)d_in[4];
    const float* Wks  = (const float*)d_in[5];
    const float* Wvs  = (const float*)d_in[6];
    const float* Wqe  = (const float*)d_in[7];
    const float* Wke  = (const float*)d_in[8];
    const float* Wve  = (const float*)d_in[9];
    const float* g0   = (const float*)d_in[10];
    const float* b0   = (const float*)d_in[11];
    const float* gs   = (const float*)d_in[12];
    const float* bs   = (const float*)d_in[13];
    const float* ge   = (const float*)d_in[14];
    const float* be   = (const float*)d_in[15];
    const float* cope = (const float*)d_in[16];

    float* qf = (float*)d_ws;
    float* kf = qf + (size_t)B_ * L_ * DK;
    float* vf = kf + (size_t)B_ * L_ * DK;
    float* out = (float*)d_out;

    k_lnproj<<<B_ * L_, 256, 0, stream>>>(x,
        Wq, Wk, Wv, Wqs, Wks, Wvs, Wqe, Wke, Wve,
        g0, b0, gs, bs, ge, be, qf, kf, vf);
    k_attn_mid<<<B_ * (SEQ_ / QT), 256, 0, stream>>>(qf, kf, vf, cope, out);
    k_attn_edge<<<B_ * 2 * S_, 256, 0, stream>>>(qf, kf, vf, out);
}

// Round 3
// 409.099 us; speedup vs baseline: 3.8620x; 1.6356x over previous
//
#include <hip/hip_runtime.h>
#include <math.h>

#define B_    4
#define SEQ_  2048
#define S_    128
#define L_    2304          // SEQ + 2*S
#define DIN   512
#define DK    64
#define NEGINF (-1e30f)
#define SCALE 0.125f
#define NCOLS 2176          // start(128) + mid(2048) key columns in D
#define NMID  8192          // B_*SEQ_

// ---------------------------------------------------------------------------
// k_ln: wave-per-row LayerNorm. grid 2304 x 256 (4 rows/block). No LDS.
// ---------------------------------------------------------------------------
__global__ __launch_bounds__(256) void k_ln(
    const float* __restrict__ x,
    const float* __restrict__ g0, const float* __restrict__ b0,
    const float* __restrict__ gs, const float* __restrict__ bs,
    const float* __restrict__ ge, const float* __restrict__ be,
    float* __restrict__ xn)
{
    const int wave = threadIdx.x >> 6, lane = threadIdx.x & 63;
    const int row  = blockIdx.x * 4 + wave;
    const float4* xr = (const float4*)(x + (size_t)row * DIN);
    float4 v0 = xr[lane], v1 = xr[lane + 64];
    float s  = v0.x + v0.y + v0.z + v0.w + v1.x + v1.y + v1.z + v1.w;
    float s2 = v0.x*v0.x + v0.y*v0.y + v0.z*v0.z + v0.w*v0.w
             + v1.x*v1.x + v1.y*v1.y + v1.z*v1.z + v1.w*v1.w;
    #pragma unroll
    for (int m = 1; m < 64; m <<= 1) { s += __shfl_xor(s, m); s2 += __shfl_xor(s2, m); }
    float mean = s * (1.f / DIN);
    float var  = s2 * (1.f / DIN) - mean * mean;
    float rstd = rsqrtf(var + 1e-5f);

    const int r = row % L_;
    const float *gg, *bb;
    if (r < S_)            { gg = gs; bb = bs; }
    else if (r >= L_ - S_) { gg = ge; bb = be; }
    else                   { gg = g0; bb = b0; }
    float4 ga = ((const float4*)gg)[lane], gb = ((const float4*)gg)[lane + 64];
    float4 ba = ((const float4*)bb)[lane], bb4 = ((const float4*)bb)[lane + 64];
    float4 o0, o1;
    o0.x = (v0.x - mean) * rstd * ga.x + ba.x;
    o0.y = (v0.y - mean) * rstd * ga.y + ba.y;
    o0.z = (v0.z - mean) * rstd * ga.z + ba.z;
    o0.w = (v0.w - mean) * rstd * ga.w + ba.w;
    o1.x = (v1.x - mean) * rstd * gb.x + bb4.x;
    o1.y = (v1.y - mean) * rstd * gb.y + bb4.y;
    o1.z = (v1.z - mean) * rstd * gb.z + bb4.z;
    o1.w = (v1.w - mean) * rstd * gb.w + bb4.w;
    float4* xo = (float4*)(xn + (size_t)row * DIN);
    xo[lane] = o0; xo[lane + 64] = o1;
}

// ---------------------------------------------------------------------------
// k_proj: QKV projection GEMM. grid (144,3) x 256. Tile 64 rows x 64 cols.
// ---------------------------------------------------------------------------
__global__ __launch_bounds__(256) void k_proj(
    const float* __restrict__ xn,
    const float* __restrict__ Wq,  const float* __restrict__ Wk,  const float* __restrict__ Wv,
    const float* __restrict__ Wqs, const float* __restrict__ Wks, const float* __restrict__ Wvs,
    const float* __restrict__ Wqe, const float* __restrict__ Wke, const float* __restrict__ Wve,
    float* __restrict__ qf, float* __restrict__ kf, float* __restrict__ vf)
{
    __shared__ float xs[64 * 68];
    __shared__ float ws_[64 * 68];
    const int tid  = threadIdx.x;
    const int row0 = blockIdx.x * 64;
    const int rseq = row0 % L_;
    const int seg  = (rseq < S_) ? 0 : (rseq >= L_ - S_) ? 2 : 1;
    const int m    = blockIdx.y;
    const float* W;
    float* out;
    if (m == 0)      { W = (seg == 0) ? Wqs : (seg == 2) ? Wqe : Wq; out = qf; }
    else if (m == 1) { W = (seg == 0) ? Wks : (seg == 2) ? Wke : Wk; out = kf; }
    else             { W = (seg == 0) ? Wvs : (seg == 2) ? Wve : Wv; out = vf; }

    const int c4 = tid & 15, r4 = tid >> 4;   // cols c0=4c4, rows r0=4r4
    float acc[4][4] = {};

    for (int kc = 0; kc < DIN; kc += 64) {
        __syncthreads();
        #pragma unroll
        for (int i = 0; i < 4; ++i) {
            int g = tid + 256 * i;            // 1024 f4: 64 rows x 16 f4
            int r = g >> 4, f = g & 15;
            *(float4*)(xs + r * 68 + f * 4) =
                ((const float4*)xn)[(size_t)(row0 + r) * (DIN / 4) + kc / 4 + f];
        }
        #pragma unroll
        for (int i = 0; i < 4; ++i) {
            int g = tid + 256 * i;            // 64 k x 16 f4
            int k = g >> 4, f = g & 15;
            *(float4*)(ws_ + k * 68 + f * 4) =
                ((const float4*)W)[(size_t)(kc + k) * (DK / 4) + f];
        }
        __syncthreads();
        #pragma unroll 4
        for (int k = 0; k < 64; ++k) {
            float4 wv = *(const float4*)(ws_ + k * 68 + c4 * 4);
            #pragma unroll
            for (int i = 0; i < 4; ++i) {
                float a = xs[(r4 * 4 + i) * 68 + k];
                acc[i][0] += a * wv.x; acc[i][1] += a * wv.y;
                acc[i][2] += a * wv.z; acc[i][3] += a * wv.w;
            }
        }
    }
    #pragma unroll
    for (int i = 0; i < 4; ++i) {
        float4 o = make_float4(acc[i][0], acc[i][1], acc[i][2], acc[i][3]);
        *(float4*)(out + (size_t)(row0 + r4 * 4 + i) * DK + c4 * 4) = o;
    }
}

// ---------------------------------------------------------------------------
// k_cope: Li[gr][p] = q_mid[gr] . cope[:,p]. grid 256 x 256 (32 rows x 128 p).
// ---------------------------------------------------------------------------
__global__ __launch_bounds__(256) void k_cope(
    const float* __restrict__ qf, const float* __restrict__ cope,
    float* __restrict__ Li)
{
    __shared__ float qs[32 * 68];
    const int tid = threadIdx.x;
    const int gr0 = blockIdx.x * 32;
    const int b   = gr0 >> 11;
    const size_t qrow0 = (size_t)b * L_ + S_ + (gr0 & 2047);
    #pragma unroll
    for (int i = 0; i < 2; ++i) {
        int g = tid + 256 * i;                // 512 f4
        int r = g >> 4, f = g & 15;
        *(float4*)(qs + r * 68 + f * 4) = ((const float4*)qf)[(qrow0 + r) * 16 + f];
    }
    __syncthreads();
    const int c4 = tid & 31, r4 = tid >> 5;   // cols c0=4c4 (0..127), rows r0=4r4
    float acc[4][4] = {};
    for (int d = 0; d < DK; ++d) {
        float4 cv = ((const float4*)cope)[d * 32 + c4];
        #pragma unroll
        for (int i = 0; i < 4; ++i) {
            float a = qs[(r4 * 4 + i) * 68 + d];
            acc[i][0] += a * cv.x; acc[i][1] += a * cv.y;
            acc[i][2] += a * cv.z; acc[i][3] += a * cv.w;
        }
    }
    #pragma unroll
    for (int i = 0; i < 4; ++i)
        *(float4*)(Li + (size_t)(gr0 + r4 * 4 + i) * 128 + c4 * 4) =
            make_float4(acc[i][0], acc[i][1], acc[i][2], acc[i][3]);
}

// ---------------------------------------------------------------------------
// k_dots: D[gr][col] = q_mid[gr] . k[col] (raw). grid (64,17) x 256.
// Tile 128 rows x 128 cols, 8x8 register tile, K transposed in LDS.
// ---------------------------------------------------------------------------
__global__ __launch_bounds__(256) void k_dots(
    const float* __restrict__ qf, const float* __restrict__ kf,
    float* __restrict__ D)
{
    __shared__ float Qs[128 * 68];   // [r][d]
    __shared__ float Kt[64 * 136];   // [d][j]
    const int tid  = threadIdx.x;
    const int gr0  = blockIdx.x * 128;
    const int col0 = blockIdx.y * 128;
    const int b    = gr0 >> 11;
    const size_t qrow0 = (size_t)b * L_ + S_ + (gr0 & 2047);
    const size_t krow0 = (size_t)b * L_ + col0;

    #pragma unroll
    for (int i = 0; i < 8; ++i) {
        int g = tid + 256 * i;               // 2048 f4: 128 rows x 16 f4
        int r = g >> 4, f = g & 15;
        *(float4*)(Qs + r * 68 + f * 4) = ((const float4*)qf)[(qrow0 + r) * 16 + f];
    }
    #pragma unroll
    for (int i = 0; i < 8; ++i) {
        int g = tid + 256 * i;               // 128 j x 16 f4, transpose to Kt
        int j = g >> 4, f = g & 15;
        float4 kv = ((const float4*)kf)[(krow0 + j) * 16 + f];
        Kt[(f * 4 + 0) * 136 + j] = kv.x;
        Kt[(f * 4 + 1) * 136 + j] = kv.y;
        Kt[(f * 4 + 2) * 136 + j] = kv.z;
        Kt[(f * 4 + 3) * 136 + j] = kv.w;
    }
    __syncthreads();

    const int c8 = tid & 15, r8 = tid >> 4;  // j0 = 8c8, r0 = 8r8
    float acc[8][8] = {};
    for (int d0 = 0; d0 < 64; d0 += 4) {
        float4 a[8];
        #pragma unroll
        for (int i = 0; i < 8; ++i)
            a[i] = *(const float4*)(Qs + (r8 * 8 + i) * 68 + d0);
        #pragma unroll
        for (int dd = 0; dd < 4; ++dd) {
            float4 k0 = *(const float4*)(Kt + (d0 + dd) * 136 + c8 * 8);
            float4 k1 = *(const float4*)(Kt + (d0 + dd) * 136 + c8 * 8 + 4);
            #pragma unroll
            for (int i = 0; i < 8; ++i) {
                float av = (dd == 0) ? a[i].x : (dd == 1) ? a[i].y : (dd == 2) ? a[i].z : a[i].w;
                acc[i][0] += av * k0.x; acc[i][1] += av * k0.y;
                acc[i][2] += av * k0.z; acc[i][3] += av * k0.w;
                acc[i][4] += av * k1.x; acc[i][5] += av * k1.y;
                acc[i][6] += av * k1.z; acc[i][7] += av * k1.w;
            }
        }
    }
    #pragma unroll
    for (int i = 0; i < 8; ++i) {
        size_t o = (size_t)(gr0 + r8 * 8 + i) * NCOLS + col0 + c8 * 8;
        *(float4*)(D + o)     = make_float4(acc[i][0], acc[i][1], acc[i][2], acc[i][3]);
        *(float4*)(D + o + 4) = make_float4(acc[i][4], acc[i][5], acc[i][6], acc[i][7]);
    }
}

// ---------------------------------------------------------------------------
// k_scan: per mid-row gates -> suffix scan -> CoPE bias -> softmax.
// Reads raw D row, writes normalized P in place. grid 8192 x 256.
// ---------------------------------------------------------------------------
__global__ __launch_bounds__(256) void k_scan(
    const float* __restrict__ Li, float* __restrict__ D)
{
    __shared__ float ds[NCOLS];
    __shared__ float li[128];
    __shared__ float red[256];
    const int tid = threadIdx.x;
    const int gr  = blockIdx.x;
    const int q   = gr & 2047;
    const size_t rowoff = (size_t)gr * NCOLS;

    for (int g = tid; g < NCOLS / 4; g += 256)
        ((float4*)ds)[g] = ((const float4*)(D + rowoff))[g];
    if (tid < 32) ((float4*)li)[tid] = ((const float4*)(Li + (size_t)gr * 128))[tid];
    __syncthreads();

    const int j0 = tid * 8;                  // mid-local chunk
    float dot[8], gte[8];
    *(float4*)&dot[0] = *(const float4*)(ds + 128 + j0);
    *(float4*)&dot[4] = *(const float4*)(ds + 128 + j0 + 4);
    float csum = 0.f;
    #pragma unroll
    for (int jj = 0; jj < 8; ++jj) {
        gte[jj] = 1.f / (1.f + __expf(-dot[jj]));
        csum += gte[jj];
    }
    red[tid] = csum;
    __syncthreads();
    for (int off = 1; off < 256; off <<= 1) {
        float v = red[tid] + ((tid + off < 256) ? red[tid + off] : 0.f);
        __syncthreads();
        red[tid] = v;
        __syncthreads();
    }
    float run = (tid < 255) ? red[tid + 1] : 0.f;

    float p8[8];
    #pragma unroll
    for (int jj = 7; jj >= 0; --jj) {
        run += gte[jj];
        float pos = fminf(run, (float)(S_ - 1));
        float pfl = floorf(pos);
        int ic  = (int)ceilf(pos);
        int ifl = (int)pfl;
        float w = pos - pfl;
        float bias = li[ic] * w + li[ifl] * (1.f - w);
        p8[jj] = (j0 + jj <= q) ? dot[jj] * SCALE + bias : NEGINF;
    }
    float sv = (tid < 128) ? ds[tid] * SCALE : NEGINF;

    // max
    float mx = sv;
    #pragma unroll
    for (int jj = 0; jj < 8; ++jj) mx = fmaxf(mx, p8[jj]);
    red[tid] = mx;
    __syncthreads();
    for (int off = 128; off > 0; off >>= 1) {
        if (tid < off) red[tid] = fmaxf(red[tid], red[tid + off]);
        __syncthreads();
    }
    mx = red[0];
    __syncthreads();

    // exp + sum
    float lsum = 0.f;
    float e8[8];
    #pragma unroll
    for (int jj = 0; jj < 8; ++jj) {
        e8[jj] = __expf(p8[jj] - mx);
        lsum += e8[jj];
    }
    *(float4*)(ds + 128 + j0)     = make_float4(e8[0], e8[1], e8[2], e8[3]);
    *(float4*)(ds + 128 + j0 + 4) = make_float4(e8[4], e8[5], e8[6], e8[7]);
    if (tid < 128) {
        float e = __expf(sv - mx);
        ds[tid] = e;
        lsum += e;
    }
    red[tid] = lsum;
    __syncthreads();
    for (int off = 128; off > 0; off >>= 1) {
        if (tid < off) red[tid] += red[tid + off];
        __syncthreads();
    }
    float inv = 1.f / red[0];
    __syncthreads();

    for (int g = tid; g < NCOLS / 4; g += 256) {
        float4 v = ((float4*)ds)[g];
        v.x *= inv; v.y *= inv; v.z *= inv; v.w *= inv;
        ((float4*)(D + rowoff))[g] = v;
    }
}

// ---------------------------------------------------------------------------
// k_pv: partial O = P @ V with 4-way K-split. grid (256,4) x 256.
// Tile 32 rows x 64 cols; chunk = 64 keys; P has exact zeros past causal.
// ---------------------------------------------------------------------------
__global__ __launch_bounds__(256) void k_pv(
    const float* __restrict__ D, const float* __restrict__ vf,
    float* __restrict__ Opart)
{
    __shared__ float Ps[32 * 68];
    __shared__ float Vs[64 * 68];
    const int tid = threadIdx.x;
    const int gr0 = blockIdx.x * 32;
    const int ks  = blockIdx.y;
    const int b   = gr0 >> 11, q0 = gr0 & 2047;
    const int cmax  = (159 + q0) >> 6;          // last chunk with visible keys
    const int c_beg = ks * 9;
    int c_end = c_beg + 9;
    if (c_end > 34) c_end = 34;
    if (c_end > cmax + 1) c_end = cmax + 1;

    const int c4 = tid & 15, rg = tid >> 4;     // cols c0=4c4, rows r0=2rg
    float acc[2][4] = {};

    for (int ch = c_beg; ch < c_end; ++ch) {
        __syncthreads();
        #pragma unroll
        for (int i = 0; i < 2; ++i) {
            int g = tid + 256 * i;              // 32 rows x 16 f4
            int r = g >> 4, f = g & 15;
            *(float4*)(Ps + r * 68 + f * 4) =
                *(const float4*)(D + (size_t)(gr0 + r) * NCOLS + ch * 64 + f * 4);
        }
        #pragma unroll
        for (int i = 0; i < 4; ++i) {
            int g = tid + 256 * i;              // 64 rows x 16 f4
            int j = g >> 4, f = g & 15;
            *(float4*)(Vs + j * 68 + f * 4) =
                *(const float4*)(vf + (size_t)(b * L_ + ch * 64 + j) * DK + f * 4);
        }
        __syncthreads();
        #pragma unroll 4
        for (int j = 0; j < 64; ++j) {
            float4 vv = *(const float4*)(Vs + j * 68 + c4 * 4);
            float p0 = Ps[(rg * 2 + 0) * 68 + j];
            float p1 = Ps[(rg * 2 + 1) * 68 + j];
            acc[0][0] += p0 * vv.x; acc[0][1] += p0 * vv.y;
            acc[0][2] += p0 * vv.z; acc[0][3] += p0 * vv.w;
            acc[1][0] += p1 * vv.x; acc[1][1] += p1 * vv.y;
            acc[1][2] += p1 * vv.z; acc[1][3] += p1 * vv.w;
        }
    }
    #pragma unroll
    for (int i = 0; i < 2; ++i)
        *(float4*)(Opart + ((size_t)ks * NMID + gr0 + rg * 2 + i) * DK + c4 * 4) =
            make_float4(acc[i][0], acc[i][1], acc[i][2], acc[i][3]);
}

// ---------------------------------------------------------------------------
// k_merge: out(mid rows) = sum of 4 partials. grid 2048 x 256.
// ---------------------------------------------------------------------------
__global__ __launch_bounds__(256) void k_merge(
    const float* __restrict__ Opart, float* __restrict__ out)
{
    const int e  = blockIdx.x * 256 + threadIdx.x;   // 0..524287
    const int gr = e >> 6, c = e & 63;
    const int b  = gr >> 11, q = gr & 2047;
    const int NP = NMID * DK;
    float s = Opart[e] + Opart[e + NP] + Opart[e + 2 * NP] + Opart[e + 3 * NP];
    out[((size_t)b * L_ + S_ + q) * DK + c] = s;
}

// ---------------------------------------------------------------------------
// k_attn_edge: start+end rows, plain causal softmax over rows 0..Q (unchanged).
// ---------------------------------------------------------------------------
__global__ __launch_bounds__(256) void k_attn_edge(
    const float* __restrict__ qf, const float* __restrict__ kf,
    const float* __restrict__ vf, float* __restrict__ out)
{
    __shared__ float qv[DK];
    __shared__ float Ks[128 * 68];
    __shared__ float sc[L_];
    __shared__ float red[256];

    const int blk = blockIdx.x;
    const int b   = blk / (2 * S_);
    const int r   = blk % (2 * S_);
    const int Q   = (r < S_) ? r : (L_ - S_ + (r - S_));
    const int tid = threadIdx.x;
    const size_t base = (size_t)b * L_ * DK;

    if (tid < DK) qv[tid] = qf[base + (size_t)Q * DK + tid];

    const int ntile = Q / 128 + 1;
    for (int t = 0; t < ntile; ++t) {
        __syncthreads();
        const float4* s4 = (const float4*)(kf + base + (size_t)t * 128 * DK);
        #pragma unroll
        for (int i = 0; i < 8; ++i) {
            int g = tid + 256 * i;
            int k = g >> 4, f = g & 15;
            *(float4*)(Ks + k * 68 + f * 4) = s4[g];
        }
        __syncthreads();
        if (tid < 128) {
            float acc = 0.f;
            const float4* q4 = (const float4*)qv;
            #pragma unroll
            for (int dd = 0; dd < 16; ++dd) {
                float4 qq = q4[dd];
                float4 kk = *(const float4*)(Ks + tid * 68 + dd * 4);
                acc += qq.x * kk.x + qq.y * kk.y + qq.z * kk.z + qq.w * kk.w;
            }
            int j = t * 128 + tid;
            sc[j] = (j <= Q) ? acc * SCALE : NEGINF;
        }
    }
    __syncthreads();
    for (int j = tid; j < L_; j += 256) if (j > Q) sc[j] = NEGINF;
    __syncthreads();

    const int j0 = tid * 9;
    float mx = NEGINF;
    #pragma unroll
    for (int jj = 0; jj < 9; ++jj) mx = fmaxf(mx, sc[j0 + jj]);
    red[tid] = mx;
    __syncthreads();
    for (int off = 128; off > 0; off >>= 1) {
        if (tid < off) red[tid] = fmaxf(red[tid], red[tid + off]);
        __syncthreads();
    }
    mx = red[0];
    __syncthreads();

    float lsum = 0.f;
    #pragma unroll
    for (int jj = 0; jj < 9; ++jj) {
        float e = __expf(sc[j0 + jj] - mx);
        sc[j0 + jj] = e;
        lsum += e;
    }
    red[tid] = lsum;
    __syncthreads();
    for (int off = 128; off > 0; off >>= 1) {
        if (tid < off) red[tid] += red[tid + off];
        __syncthreads();
    }
    float denom = red[0];
    __syncthreads();

    const int d = tid & 63, grp = tid >> 6;
    float acc = 0.f;
    const float* vr = vf + base;
    for (int j = grp; j <= Q; j += 4) acc += sc[j] * vr[(size_t)j * DK + d];
    red[tid] = acc;
    __syncthreads();
    if (tid < 64) {
        float o = red[tid] + red[tid + 64] + red[tid + 128] + red[tid + 192];
        out[((size_t)b * L_ + Q) * DK + tid] = o / denom;
    }
}

// ---------------------------------------------------------------------------
extern "C" void kernel_launch(void* const* d_in, const int* in_sizes, int n_in,
                              void* d_out, int out_size, void* d_ws, size_t ws_size,
                              hipStream_t stream)
{
    const float* x    = (const float*)d_in[0];
    const float* Wq   = (const float*)d_in[1];
    const float* Wk   = (const float*)d_in[2];
    const float* Wv   = (const float*)d_in[3];
    const float* Wqs  = (const float*)d_in[4];
    const float* Wks  = (const float*)d_in[5];
    const float* Wvs  = (const float*)d_in[6];
    const float* Wqe  = (const float*)d_in[7];
    const float* Wke  = (const float*)d_in[8];
    const float* Wve  = (const float*)d_in[9];
    const float* g0   = (const float*)d_in[10];
    const float* b0   = (const float*)d_in[11];
    const float* gs   = (const float*)d_in[12];
    const float* bs   = (const float*)d_in[13];
    const float* ge   = (const float*)d_in[14];
    const float* be   = (const float*)d_in[15];
    const float* cope = (const float*)d_in[16];

    float* ws = (float*)d_ws;
    float* qf    = ws;                               // 9216*64
    float* kf    = qf + (size_t)9216 * DK;
    float* vf    = kf + (size_t)9216 * DK;
    float* Li    = vf + (size_t)9216 * DK;           // 8192*128
    float* Opart = Li + (size_t)NMID * 128;          // 4*8192*64
    float* xn    = Opart + (size_t)4 * NMID * DK;    // 9216*512 (dead after k_proj)
    float* D     = xn;                               // 8192*2176 overlaps xn
    float* out   = (float*)d_out;

    k_ln  <<<L_ * B_ / 4, 256, 0, stream>>>(x, g0, b0, gs, bs, ge, be, xn);
    k_proj<<<dim3(144, 3), 256, 0, stream>>>(xn, Wq, Wk, Wv, Wqs, Wks, Wvs,
                                             Wqe, Wke, Wve, qf, kf, vf);
    k_cope<<<NMID / 32, 256, 0, stream>>>(qf, cope, Li);
    k_dots<<<dim3(NMID / 128, NCOLS / 128), 256, 0, stream>>>(qf, kf, D);
    k_scan<<<NMID, 256, 0, stream>>>(Li, D);
    k_pv  <<<dim3(NMID / 32, 4), 256, 0, stream>>>(D, vf, Opart);
    k_merge<<<NMID * DK / 256, 256, 0, stream>>>(Opart, out);
    k_attn_edge<<<B_ * 2 * S_, 256, 0, stream>>>(qf, kf, vf, out);
}

// Round 4
// 281.676 us; speedup vs baseline: 5.6090x; 1.4524x over previous
//
#include <hip/hip_runtime.h>
#include <math.h>

#define B_    4
#define SEQ_  2048
#define S_    128
#define L_    2304          // SEQ + 2*S
#define DIN   512
#define DK    64
#define NEGINF (-1e30f)
#define SCALE 0.125f
#define NCOLS 2176          // start(128) + mid(2048) key columns in D
#define NMID  8192          // B_*SEQ_
#define NEDGE 1024          // B_*2*S_
#define LE    2304          // edge D row length

// ---------------------------------------------------------------------------
// k_ln: wave-per-row LayerNorm. grid 2304 x 256 (4 rows/block). No LDS.
// ---------------------------------------------------------------------------
__global__ __launch_bounds__(256) void k_ln(
    const float* __restrict__ x,
    const float* __restrict__ g0, const float* __restrict__ b0,
    const float* __restrict__ gs, const float* __restrict__ bs,
    const float* __restrict__ ge, const float* __restrict__ be,
    float* __restrict__ xn)
{
    const int wave = threadIdx.x >> 6, lane = threadIdx.x & 63;
    const int row  = blockIdx.x * 4 + wave;
    const float4* xr = (const float4*)(x + (size_t)row * DIN);
    float4 v0 = xr[lane], v1 = xr[lane + 64];
    float s  = v0.x + v0.y + v0.z + v0.w + v1.x + v1.y + v1.z + v1.w;
    float s2 = v0.x*v0.x + v0.y*v0.y + v0.z*v0.z + v0.w*v0.w
             + v1.x*v1.x + v1.y*v1.y + v1.z*v1.z + v1.w*v1.w;
    #pragma unroll
    for (int m = 1; m < 64; m <<= 1) { s += __shfl_xor(s, m); s2 += __shfl_xor(s2, m); }
    float mean = s * (1.f / DIN);
    float var  = s2 * (1.f / DIN) - mean * mean;
    float rstd = rsqrtf(var + 1e-5f);

    const int r = row % L_;
    const float *gg, *bb;
    if (r < S_)            { gg = gs; bb = bs; }
    else if (r >= L_ - S_) { gg = ge; bb = be; }
    else                   { gg = g0; bb = b0; }
    float4 ga = ((const float4*)gg)[lane], gb = ((const float4*)gg)[lane + 64];
    float4 ba = ((const float4*)bb)[lane], bb4 = ((const float4*)bb)[lane + 64];
    float4 o0, o1;
    o0.x = (v0.x - mean) * rstd * ga.x + ba.x;
    o0.y = (v0.y - mean) * rstd * ga.y + ba.y;
    o0.z = (v0.z - mean) * rstd * ga.z + ba.z;
    o0.w = (v0.w - mean) * rstd * ga.w + ba.w;
    o1.x = (v1.x - mean) * rstd * gb.x + bb4.x;
    o1.y = (v1.y - mean) * rstd * gb.y + bb4.y;
    o1.z = (v1.z - mean) * rstd * gb.z + bb4.z;
    o1.w = (v1.w - mean) * rstd * gb.w + bb4.w;
    float4* xo = (float4*)(xn + (size_t)row * DIN);
    xo[lane] = o0; xo[lane + 64] = o1;
}

// ---------------------------------------------------------------------------
// k_proj: QKV projection GEMM. grid (144,3) x 256. Tile 64 rows x 64 cols.
// ---------------------------------------------------------------------------
__global__ __launch_bounds__(256) void k_proj(
    const float* __restrict__ xn,
    const float* __restrict__ Wq,  const float* __restrict__ Wk,  const float* __restrict__ Wv,
    const float* __restrict__ Wqs, const float* __restrict__ Wks, const float* __restrict__ Wvs,
    const float* __restrict__ Wqe, const float* __restrict__ Wke, const float* __restrict__ Wve,
    float* __restrict__ qf, float* __restrict__ kf, float* __restrict__ vf)
{
    __shared__ float xs[64 * 68];
    __shared__ float ws_[64 * 68];
    const int tid  = threadIdx.x;
    const int row0 = blockIdx.x * 64;
    const int rseq = row0 % L_;
    const int seg  = (rseq < S_) ? 0 : (rseq >= L_ - S_) ? 2 : 1;
    const int m    = blockIdx.y;
    const float* W;
    float* out;
    if (m == 0)      { W = (seg == 0) ? Wqs : (seg == 2) ? Wqe : Wq; out = qf; }
    else if (m == 1) { W = (seg == 0) ? Wks : (seg == 2) ? Wke : Wk; out = kf; }
    else             { W = (seg == 0) ? Wvs : (seg == 2) ? Wve : Wv; out = vf; }

    const int c4 = tid & 15, r4 = tid >> 4;
    float acc[4][4] = {};

    for (int kc = 0; kc < DIN; kc += 64) {
        __syncthreads();
        #pragma unroll
        for (int i = 0; i < 4; ++i) {
            int g = tid + 256 * i;
            int r = g >> 4, f = g & 15;
            *(float4*)(xs + r * 68 + f * 4) =
                ((const float4*)xn)[(size_t)(row0 + r) * (DIN / 4) + kc / 4 + f];
        }
        #pragma unroll
        for (int i = 0; i < 4; ++i) {
            int g = tid + 256 * i;
            int k = g >> 4, f = g & 15;
            *(float4*)(ws_ + k * 68 + f * 4) =
                ((const float4*)W)[(size_t)(kc + k) * (DK / 4) + f];
        }
        __syncthreads();
        #pragma unroll 4
        for (int k = 0; k < 64; ++k) {
            float4 wv = *(const float4*)(ws_ + k * 68 + c4 * 4);
            #pragma unroll
            for (int i = 0; i < 4; ++i) {
                float a = xs[(r4 * 4 + i) * 68 + k];
                acc[i][0] += a * wv.x; acc[i][1] += a * wv.y;
                acc[i][2] += a * wv.z; acc[i][3] += a * wv.w;
            }
        }
    }
    #pragma unroll
    for (int i = 0; i < 4; ++i) {
        float4 o = make_float4(acc[i][0], acc[i][1], acc[i][2], acc[i][3]);
        *(float4*)(out + (size_t)(row0 + r4 * 4 + i) * DK + c4 * 4) = o;
    }
}

// ---------------------------------------------------------------------------
// k_cope: Li[gr][p] = q_mid[gr] . cope[:,p]. grid 256 x 256.
// ---------------------------------------------------------------------------
__global__ __launch_bounds__(256) void k_cope(
    const float* __restrict__ qf, const float* __restrict__ cope,
    float* __restrict__ Li)
{
    __shared__ float qs[32 * 68];
    const int tid = threadIdx.x;
    const int gr0 = blockIdx.x * 32;
    const int b   = gr0 >> 11;
    const size_t qrow0 = (size_t)b * L_ + S_ + (gr0 & 2047);
    #pragma unroll
    for (int i = 0; i < 2; ++i) {
        int g = tid + 256 * i;
        int r = g >> 4, f = g & 15;
        *(float4*)(qs + r * 68 + f * 4) = ((const float4*)qf)[(qrow0 + r) * 16 + f];
    }
    __syncthreads();
    const int c4 = tid & 31, r4 = tid >> 5;
    float acc[4][4] = {};
    for (int d = 0; d < DK; ++d) {
        float4 cv = ((const float4*)cope)[d * 32 + c4];
        #pragma unroll
        for (int i = 0; i < 4; ++i) {
            float a = qs[(r4 * 4 + i) * 68 + d];
            acc[i][0] += a * cv.x; acc[i][1] += a * cv.y;
            acc[i][2] += a * cv.z; acc[i][3] += a * cv.w;
        }
    }
    #pragma unroll
    for (int i = 0; i < 4; ++i)
        *(float4*)(Li + (size_t)(gr0 + r4 * 4 + i) * 128 + c4 * 4) =
            make_float4(acc[i][0], acc[i][1], acc[i][2], acc[i][3]);
}

// ---------------------------------------------------------------------------
// k_dots: D[gr][col] = q_mid[gr] . k[col]. grid (64,17) x 256.
// ---------------------------------------------------------------------------
__global__ __launch_bounds__(256) void k_dots(
    const float* __restrict__ qf, const float* __restrict__ kf,
    float* __restrict__ D)
{
    __shared__ float Qs[128 * 68];
    __shared__ float Kt[64 * 136];
    const int tid  = threadIdx.x;
    const int gr0  = blockIdx.x * 128;
    const int col0 = blockIdx.y * 128;
    const int b    = gr0 >> 11;
    const size_t qrow0 = (size_t)b * L_ + S_ + (gr0 & 2047);
    const size_t krow0 = (size_t)b * L_ + col0;

    #pragma unroll
    for (int i = 0; i < 8; ++i) {
        int g = tid + 256 * i;
        int r = g >> 4, f = g & 15;
        *(float4*)(Qs + r * 68 + f * 4) = ((const float4*)qf)[(qrow0 + r) * 16 + f];
    }
    #pragma unroll
    for (int i = 0; i < 8; ++i) {
        int g = tid + 256 * i;
        int j = g >> 4, f = g & 15;
        float4 kv = ((const float4*)kf)[(krow0 + j) * 16 + f];
        Kt[(f * 4 + 0) * 136 + j] = kv.x;
        Kt[(f * 4 + 1) * 136 + j] = kv.y;
        Kt[(f * 4 + 2) * 136 + j] = kv.z;
        Kt[(f * 4 + 3) * 136 + j] = kv.w;
    }
    __syncthreads();

    const int c8 = tid & 15, r8 = tid >> 4;
    float acc[8][8] = {};
    for (int d0 = 0; d0 < 64; d0 += 4) {
        float4 a[8];
        #pragma unroll
        for (int i = 0; i < 8; ++i)
            a[i] = *(const float4*)(Qs + (r8 * 8 + i) * 68 + d0);
        #pragma unroll
        for (int dd = 0; dd < 4; ++dd) {
            float4 k0 = *(const float4*)(Kt + (d0 + dd) * 136 + c8 * 8);
            float4 k1 = *(const float4*)(Kt + (d0 + dd) * 136 + c8 * 8 + 4);
            #pragma unroll
            for (int i = 0; i < 8; ++i) {
                float av = (dd == 0) ? a[i].x : (dd == 1) ? a[i].y : (dd == 2) ? a[i].z : a[i].w;
                acc[i][0] += av * k0.x; acc[i][1] += av * k0.y;
                acc[i][2] += av * k0.z; acc[i][3] += av * k0.w;
                acc[i][4] += av * k1.x; acc[i][5] += av * k1.y;
                acc[i][6] += av * k1.z; acc[i][7] += av * k1.w;
            }
        }
    }
    #pragma unroll
    for (int i = 0; i < 8; ++i) {
        size_t o = (size_t)(gr0 + r8 * 8 + i) * NCOLS + col0 + c8 * 8;
        *(float4*)(D + o)     = make_float4(acc[i][0], acc[i][1], acc[i][2], acc[i][3]);
        *(float4*)(D + o + 4) = make_float4(acc[i][4], acc[i][5], acc[i][6], acc[i][7]);
    }
}

// ---------------------------------------------------------------------------
// k_scan: gates -> suffix scan (shfl) -> CoPE bias -> softmax. grid 8192.
// ---------------------------------------------------------------------------
__global__ __launch_bounds__(256) void k_scan(
    const float* __restrict__ Li, float* __restrict__ D)
{
    __shared__ float ds[NCOLS];
    __shared__ float li[128];
    __shared__ float red[256];
    __shared__ float wtot[4];
    const int tid = threadIdx.x;
    const int gr  = blockIdx.x;
    const int q   = gr & 2047;
    const size_t rowoff = (size_t)gr * NCOLS;

    for (int g = tid; g < NCOLS / 4; g += 256)
        ((float4*)ds)[g] = ((const float4*)(D + rowoff))[g];
    if (tid < 32) ((float4*)li)[tid] = ((const float4*)(Li + (size_t)gr * 128))[tid];
    __syncthreads();

    const int j0 = tid * 8;
    float dot[8], gte[8];
    *(float4*)&dot[0] = *(const float4*)(ds + 128 + j0);
    *(float4*)&dot[4] = *(const float4*)(ds + 128 + j0 + 4);
    float csum = 0.f;
    #pragma unroll
    for (int jj = 0; jj < 8; ++jj) {
        gte[jj] = 1.f / (1.f + __expf(-dot[jj]));
        csum += gte[jj];
    }
    // wave-level inclusive suffix scan of chunk sums
    const int lane = tid & 63, wid = tid >> 6;
    float inc = csum;
    #pragma unroll
    for (int off = 1; off < 64; off <<= 1) {
        float u = __shfl_down(inc, off, 64);
        if (lane + off < 64) inc += u;
    }
    if (lane == 0) wtot[wid] = inc;
    __syncthreads();
    float wsuf = 0.f;
    #pragma unroll
    for (int w = 0; w < 4; ++w) if (w > wid) wsuf += wtot[w];
    float run = inc - csum + wsuf;           // exclusive suffix across block

    float p8[8];
    #pragma unroll
    for (int jj = 7; jj >= 0; --jj) {
        run += gte[jj];
        float pos = fminf(run, (float)(S_ - 1));
        float pfl = floorf(pos);
        int ic  = (int)ceilf(pos);
        int ifl = (int)pfl;
        float w = pos - pfl;
        float bias = li[ic] * w + li[ifl] * (1.f - w);
        p8[jj] = (j0 + jj <= q) ? dot[jj] * SCALE + bias : NEGINF;
    }
    float sv = (tid < 128) ? ds[tid] * SCALE : NEGINF;

    float mx = sv;
    #pragma unroll
    for (int jj = 0; jj < 8; ++jj) mx = fmaxf(mx, p8[jj]);
    red[tid] = mx;
    __syncthreads();
    for (int off = 128; off > 0; off >>= 1) {
        if (tid < off) red[tid] = fmaxf(red[tid], red[tid + off]);
        __syncthreads();
    }
    mx = red[0];
    __syncthreads();

    float lsum = 0.f;
    float e8[8];
    #pragma unroll
    for (int jj = 0; jj < 8; ++jj) {
        e8[jj] = __expf(p8[jj] - mx);
        lsum += e8[jj];
    }
    *(float4*)(ds + 128 + j0)     = make_float4(e8[0], e8[1], e8[2], e8[3]);
    *(float4*)(ds + 128 + j0 + 4) = make_float4(e8[4], e8[5], e8[6], e8[7]);
    if (tid < 128) {
        float e = __expf(sv - mx);
        ds[tid] = e;
        lsum += e;
    }
    red[tid] = lsum;
    __syncthreads();
    for (int off = 128; off > 0; off >>= 1) {
        if (tid < off) red[tid] += red[tid + off];
        __syncthreads();
    }
    float inv = 1.f / red[0];
    __syncthreads();

    for (int g = tid; g < NCOLS / 4; g += 256) {
        float4 v = ((float4*)ds)[g];
        v.x *= inv; v.y *= inv; v.z *= inv; v.w *= inv;
        ((float4*)(D + rowoff))[g] = v;
    }
}

// ---------------------------------------------------------------------------
// k_pv: partial O = P @ V with 4-way K-split. grid (256,4) x 256.
// ---------------------------------------------------------------------------
__global__ __launch_bounds__(256) void k_pv(
    const float* __restrict__ D, const float* __restrict__ vf,
    float* __restrict__ Opart)
{
    __shared__ float Ps[32 * 68];
    __shared__ float Vs[64 * 68];
    const int tid = threadIdx.x;
    const int gr0 = blockIdx.x * 32;
    const int ks  = blockIdx.y;
    const int b   = gr0 >> 11, q0 = gr0 & 2047;
    const int cmax  = (159 + q0) >> 6;
    const int c_beg = ks * 9;
    int c_end = c_beg + 9;
    if (c_end > 34) c_end = 34;
    if (c_end > cmax + 1) c_end = cmax + 1;

    const int c4 = tid & 15, rg = tid >> 4;
    float acc[2][4] = {};

    for (int ch = c_beg; ch < c_end; ++ch) {
        __syncthreads();
        #pragma unroll
        for (int i = 0; i < 2; ++i) {
            int g = tid + 256 * i;
            int r = g >> 4, f = g & 15;
            *(float4*)(Ps + r * 68 + f * 4) =
                *(const float4*)(D + (size_t)(gr0 + r) * NCOLS + ch * 64 + f * 4);
        }
        #pragma unroll
        for (int i = 0; i < 4; ++i) {
            int g = tid + 256 * i;
            int j = g >> 4, f = g & 15;
            *(float4*)(Vs + j * 68 + f * 4) =
                *(const float4*)(vf + (size_t)(b * L_ + ch * 64 + j) * DK + f * 4);
        }
        __syncthreads();
        #pragma unroll 4
        for (int j = 0; j < 64; ++j) {
            float4 vv = *(const float4*)(Vs + j * 68 + c4 * 4);
            float p0 = Ps[(rg * 2 + 0) * 68 + j];
            float p1 = Ps[(rg * 2 + 1) * 68 + j];
            acc[0][0] += p0 * vv.x; acc[0][1] += p0 * vv.y;
            acc[0][2] += p0 * vv.z; acc[0][3] += p0 * vv.w;
            acc[1][0] += p1 * vv.x; acc[1][1] += p1 * vv.y;
            acc[1][2] += p1 * vv.z; acc[1][3] += p1 * vv.w;
        }
    }
    #pragma unroll
    for (int i = 0; i < 2; ++i)
        *(float4*)(Opart + ((size_t)ks * NMID + gr0 + rg * 2 + i) * DK + c4 * 4) =
            make_float4(acc[i][0], acc[i][1], acc[i][2], acc[i][3]);
}

// ---------------------------------------------------------------------------
// k_merge: out(mid rows) = sum of 4 partials. grid 2048 x 256.
// ---------------------------------------------------------------------------
__global__ __launch_bounds__(256) void k_merge(
    const float* __restrict__ Opart, float* __restrict__ out)
{
    const int e  = blockIdx.x * 256 + threadIdx.x;
    const int gr = e >> 6, c = e & 63;
    const int b  = gr >> 11, q = gr & 2047;
    const int NP = NMID * DK;
    float s = Opart[e] + Opart[e + NP] + Opart[e + 2 * NP] + Opart[e + 3 * NP];
    out[((size_t)b * L_ + S_ + q) * DK + c] = s;
}

// ---------------------------------------------------------------------------
// k_dots_edge: De[er][col] = q_edge[er] . k[col]. grid (8,18) x 256.
// er = b*256 + r; r<128 -> start q rows (offset 0); else end q rows (2176+).
// ---------------------------------------------------------------------------
__global__ __launch_bounds__(256) void k_dots_edge(
    const float* __restrict__ qf, const float* __restrict__ kf,
    float* __restrict__ De)
{
    const int bx   = blockIdx.x;           // 0..7: two 128-row tiles per batch
    const int b    = bx >> 1;
    const int half = bx & 1;               // 0=start rows, 1=end rows
    const int col0 = blockIdx.y * 128;
    if (half == 0 && col0 > 127) return;   // start rows never see cols >=128

    __shared__ float Qs[128 * 68];
    __shared__ float Kt[64 * 136];
    const int tid = threadIdx.x;
    const int er0 = bx * 128;
    const size_t qrow0 = (size_t)b * L_ + (half ? (L_ - S_ - S_ + S_) /*2176*/ : 0);
    const size_t krow0 = (size_t)b * L_ + col0;

    #pragma unroll
    for (int i = 0; i < 8; ++i) {
        int g = tid + 256 * i;
        int r = g >> 4, f = g & 15;
        *(float4*)(Qs + r * 68 + f * 4) = ((const float4*)qf)[(qrow0 + r) * 16 + f];
    }
    #pragma unroll
    for (int i = 0; i < 8; ++i) {
        int g = tid + 256 * i;
        int j = g >> 4, f = g & 15;
        float4 kv = ((const float4*)kf)[(krow0 + j) * 16 + f];
        Kt[(f * 4 + 0) * 136 + j] = kv.x;
        Kt[(f * 4 + 1) * 136 + j] = kv.y;
        Kt[(f * 4 + 2) * 136 + j] = kv.z;
        Kt[(f * 4 + 3) * 136 + j] = kv.w;
    }
    __syncthreads();

    const int c8 = tid & 15, r8 = tid >> 4;
    float acc[8][8] = {};
    for (int d0 = 0; d0 < 64; d0 += 4) {
        float4 a[8];
        #pragma unroll
        for (int i = 0; i < 8; ++i)
            a[i] = *(const float4*)(Qs + (r8 * 8 + i) * 68 + d0);
        #pragma unroll
        for (int dd = 0; dd < 4; ++dd) {
            float4 k0 = *(const float4*)(Kt + (d0 + dd) * 136 + c8 * 8);
            float4 k1 = *(const float4*)(Kt + (d0 + dd) * 136 + c8 * 8 + 4);
            #pragma unroll
            for (int i = 0; i < 8; ++i) {
                float av = (dd == 0) ? a[i].x : (dd == 1) ? a[i].y : (dd == 2) ? a[i].z : a[i].w;
                acc[i][0] += av * k0.x; acc[i][1] += av * k0.y;
                acc[i][2] += av * k0.z; acc[i][3] += av * k0.w;
                acc[i][4] += av * k1.x; acc[i][5] += av * k1.y;
                acc[i][6] += av * k1.z; acc[i][7] += av * k1.w;
            }
        }
    }
    #pragma unroll
    for (int i = 0; i < 8; ++i) {
        size_t o = (size_t)(er0 + r8 * 8 + i) * LE + col0 + c8 * 8;
        *(float4*)(De + o)     = make_float4(acc[i][0], acc[i][1], acc[i][2], acc[i][3]);
        *(float4*)(De + o + 4) = make_float4(acc[i][4], acc[i][5], acc[i][6], acc[i][7]);
    }
}

// ---------------------------------------------------------------------------
// k_soft_edge: row-wise causal softmax on De. grid 1024 x 256.
// ---------------------------------------------------------------------------
__global__ __launch_bounds__(256) void k_soft_edge(float* __restrict__ De)
{
    __shared__ float red[256];
    const int tid = threadIdx.x;
    const int er  = blockIdx.x;
    const int r   = er & 255;
    const int Q   = (r < 128) ? r : (2048 + r);
    const size_t rowoff = (size_t)er * LE;

    float v[9];
    #pragma unroll
    for (int i = 0; i < 9; ++i) {
        int j = tid + 256 * i;
        float d = De[rowoff + j];
        v[i] = (j <= Q) ? d * SCALE : NEGINF;
    }
    float mx = v[0];
    #pragma unroll
    for (int i = 1; i < 9; ++i) mx = fmaxf(mx, v[i]);
    red[tid] = mx;
    __syncthreads();
    for (int off = 128; off > 0; off >>= 1) {
        if (tid < off) red[tid] = fmaxf(red[tid], red[tid + off]);
        __syncthreads();
    }
    mx = red[0];
    __syncthreads();

    float lsum = 0.f;
    #pragma unroll
    for (int i = 0; i < 9; ++i) {
        v[i] = __expf(v[i] - mx);
        lsum += v[i];
    }
    red[tid] = lsum;
    __syncthreads();
    for (int off = 128; off > 0; off >>= 1) {
        if (tid < off) red[tid] += red[tid + off];
        __syncthreads();
    }
    float inv = 1.f / red[0];
    #pragma unroll
    for (int i = 0; i < 9; ++i)
        De[rowoff + tid + 256 * i] = v[i] * inv;
}

// ---------------------------------------------------------------------------
// k_pv_edge: partial Oe = Pe @ V, 4-way K-split over 36 chunks. grid (32,4).
// ---------------------------------------------------------------------------
__global__ __launch_bounds__(256) void k_pv_edge(
    const float* __restrict__ De, const float* __restrict__ vf,
    float* __restrict__ Oe)
{
    __shared__ float Ps[32 * 68];
    __shared__ float Vs[64 * 68];
    const int tid = threadIdx.x;
    const int er0 = blockIdx.x * 32;
    const int ks  = blockIdx.y;
    const int b   = er0 >> 8, r0 = er0 & 255;
    const int Qmax = (r0 < 128) ? (r0 + 31) : (2048 + r0 + 31);
    const int cmax = Qmax >> 6;
    const int c_beg = ks * 9;
    int c_end = c_beg + 9;
    if (c_end > 36) c_end = 36;
    if (c_end > cmax + 1) c_end = cmax + 1;

    const int c4 = tid & 15, rg = tid >> 4;
    float acc[2][4] = {};

    for (int ch = c_beg; ch < c_end; ++ch) {
        __syncthreads();
        #pragma unroll
        for (int i = 0; i < 2; ++i) {
            int g = tid + 256 * i;
            int r = g >> 4, f = g & 15;
            *(float4*)(Ps + r * 68 + f * 4) =
                *(const float4*)(De + (size_t)(er0 + r) * LE + ch * 64 + f * 4);
        }
        #pragma unroll
        for (int i = 0; i < 4; ++i) {
            int g = tid + 256 * i;
            int j = g >> 4, f = g & 15;
            *(float4*)(Vs + j * 68 + f * 4) =
                *(const float4*)(vf + (size_t)(b * L_ + ch * 64 + j) * DK + f * 4);
        }
        __syncthreads();
        #pragma unroll 4
        for (int j = 0; j < 64; ++j) {
            float4 vv = *(const float4*)(Vs + j * 68 + c4 * 4);
            float p0 = Ps[(rg * 2 + 0) * 68 + j];
            float p1 = Ps[(rg * 2 + 1) * 68 + j];
            acc[0][0] += p0 * vv.x; acc[0][1] += p0 * vv.y;
            acc[0][2] += p0 * vv.z; acc[0][3] += p0 * vv.w;
            acc[1][0] += p1 * vv.x; acc[1][1] += p1 * vv.y;
            acc[1][2] += p1 * vv.z; acc[1][3] += p1 * vv.w;
        }
    }
    #pragma unroll
    for (int i = 0; i < 2; ++i)
        *(float4*)(Oe + ((size_t)ks * NEDGE + er0 + rg * 2 + i) * DK + c4 * 4) =
            make_float4(acc[i][0], acc[i][1], acc[i][2], acc[i][3]);
}

// ---------------------------------------------------------------------------
// k_merge_edge: out(edge rows) = sum of 4 partials. grid 256 x 256.
// ---------------------------------------------------------------------------
__global__ __launch_bounds__(256) void k_merge_edge(
    const float* __restrict__ Oe, float* __restrict__ out)
{
    const int e  = blockIdx.x * 256 + threadIdx.x;   // 0..65535
    const int er = e >> 6, c = e & 63;
    const int b  = er >> 8, r = er & 255;
    const int gQ = (r < 128) ? r : (2048 + r);
    const int NP = NEDGE * DK;
    float s = Oe[e] + Oe[e + NP] + Oe[e + 2 * NP] + Oe[e + 3 * NP];
    out[((size_t)b * L_ + gQ) * DK + c] = s;
}

// ---------------------------------------------------------------------------
extern "C" void kernel_launch(void* const* d_in, const int* in_sizes, int n_in,
                              void* d_out, int out_size, void* d_ws, size_t ws_size,
                              hipStream_t stream)
{
    const float* x    = (const float*)d_in[0];
    const float* Wq   = (const float*)d_in[1];
    const float* Wk   = (const float*)d_in[2];
    const float* Wv   = (const float*)d_in[3];
    const float* Wqs  = (const float*)d_in[4];
    const float* Wks  = (const float*)d_in[5];
    const float* Wvs  = (const float*)d_in[6];
    const float* Wqe  = (const float*)d_in[7];
    const float* Wke  = (const float*)d_in[8];
    const float* Wve  = (const float*)d_in[9];
    const float* g0   = (const float*)d_in[10];
    const float* b0   = (const float*)d_in[11];
    const float* gs   = (const float*)d_in[12];
    const float* bs   = (const float*)d_in[13];
    const float* ge   = (const float*)d_in[14];
    const float* be   = (const float*)d_in[15];
    const float* cope = (const float*)d_in[16];

    float* ws = (float*)d_ws;
    float* qf    = ws;                               // 9216*64
    float* kf    = qf + (size_t)9216 * DK;
    float* vf    = kf + (size_t)9216 * DK;
    float* Li    = vf + (size_t)9216 * DK;           // 8192*128 (dead after k_scan)
    float* Opart = Li + (size_t)NMID * 128;          // 4*8192*64
    float* xn    = Opart + (size_t)4 * NMID * DK;    // 9216*512 (dead after k_proj)
    float* D     = xn;                               // 8192*2176 overlaps xn
    float* De    = D;                                // 1024*2304 reuses D after k_pv
    float* Oe    = Li;                               // 4*1024*64 reuses Li
    float* out   = (float*)d_out;

    k_ln  <<<L_ * B_ / 4, 256, 0, stream>>>(x, g0, b0, gs, bs, ge, be, xn);
    k_proj<<<dim3(144, 3), 256, 0, stream>>>(xn, Wq, Wk, Wv, Wqs, Wks, Wvs,
                                             Wqe, Wke, Wve, qf, kf, vf);
    k_cope<<<NMID / 32, 256, 0, stream>>>(qf, cope, Li);
    k_dots<<<dim3(NMID / 128, NCOLS / 128), 256, 0, stream>>>(qf, kf, D);
    k_scan<<<NMID, 256, 0, stream>>>(Li, D);
    k_pv  <<<dim3(NMID / 32, 4), 256, 0, stream>>>(D, vf, Opart);
    k_merge<<<NMID * DK / 256, 256, 0, stream>>>(Opart, out);
    // edge path (reuses D's memory after k_pv is done)
    k_dots_edge<<<dim3(8, 18), 256, 0, stream>>>(qf, kf, De);
    k_soft_edge<<<NEDGE, 256, 0, stream>>>(De);
    k_pv_edge<<<dim3(NEDGE / 32, 4), 256, 0, stream>>>(De, vf, Oe);
    k_merge_edge<<<NEDGE * DK / 256, 256, 0, stream>>>(Oe, out);
}

// Round 5
// 241.502 us; speedup vs baseline: 6.5421x; 1.1664x over previous
//
#include <hip/hip_runtime.h>
#include <math.h>

#define B_    4
#define SEQ_  2048
#define S_    128
#define L_    2304          // SEQ + 2*S
#define DIN   512
#define DK    64
#define NEGINF (-1e30f)
#define SCALE 0.125f
#define NCOLS 2176          // start(128) + mid(2048) key columns in D
#define NMID  8192          // B_*SEQ_
#define NEDGE 1024          // B_*2*S_
#define LE    2304          // edge D row length
#define PROWS 4352          // ushorts per P row (= NCOLS*2 bytes region start of D row)

typedef __attribute__((ext_vector_type(8))) short short8;
typedef __attribute__((ext_vector_type(4))) float f32x4;

__device__ __forceinline__ unsigned short f2bf(float x) {
    union { float f; unsigned u; } c; c.f = x;
    unsigned r = c.u + 0x7FFFu + ((c.u >> 16) & 1u);
    return (unsigned short)(r >> 16);
}
__device__ __forceinline__ float bf2f(unsigned short h) {
    union { unsigned u; float f; } c; c.u = ((unsigned)h) << 16;
    return c.f;
}

// ---------------------------------------------------------------------------
// k_ln: wave-per-row LayerNorm. grid 2304 x 256 (4 rows/block).
// ---------------------------------------------------------------------------
__global__ __launch_bounds__(256) void k_ln(
    const float* __restrict__ x,
    const float* __restrict__ g0, const float* __restrict__ b0,
    const float* __restrict__ gs, const float* __restrict__ bs,
    const float* __restrict__ ge, const float* __restrict__ be,
    float* __restrict__ xn)
{
    const int wave = threadIdx.x >> 6, lane = threadIdx.x & 63;
    const int row  = blockIdx.x * 4 + wave;
    const float4* xr = (const float4*)(x + (size_t)row * DIN);
    float4 v0 = xr[lane], v1 = xr[lane + 64];
    float s  = v0.x + v0.y + v0.z + v0.w + v1.x + v1.y + v1.z + v1.w;
    float s2 = v0.x*v0.x + v0.y*v0.y + v0.z*v0.z + v0.w*v0.w
             + v1.x*v1.x + v1.y*v1.y + v1.z*v1.z + v1.w*v1.w;
    #pragma unroll
    for (int m = 1; m < 64; m <<= 1) { s += __shfl_xor(s, m); s2 += __shfl_xor(s2, m); }
    float mean = s * (1.f / DIN);
    float var  = s2 * (1.f / DIN) - mean * mean;
    float rstd = rsqrtf(var + 1e-5f);

    const int r = row % L_;
    const float *gg, *bb;
    if (r < S_)            { gg = gs; bb = bs; }
    else if (r >= L_ - S_) { gg = ge; bb = be; }
    else                   { gg = g0; bb = b0; }
    float4 ga = ((const float4*)gg)[lane], gb = ((const float4*)gg)[lane + 64];
    float4 ba = ((const float4*)bb)[lane], bb4 = ((const float4*)bb)[lane + 64];
    float4 o0, o1;
    o0.x = (v0.x - mean) * rstd * ga.x + ba.x;
    o0.y = (v0.y - mean) * rstd * ga.y + ba.y;
    o0.z = (v0.z - mean) * rstd * ga.z + ba.z;
    o0.w = (v0.w - mean) * rstd * ga.w + ba.w;
    o1.x = (v1.x - mean) * rstd * gb.x + bb4.x;
    o1.y = (v1.y - mean) * rstd * gb.y + bb4.y;
    o1.z = (v1.z - mean) * rstd * gb.z + bb4.z;
    o1.w = (v1.w - mean) * rstd * gb.w + bb4.w;
    float4* xo = (float4*)(xn + (size_t)row * DIN);
    xo[lane] = o0; xo[lane + 64] = o1;
}

// ---------------------------------------------------------------------------
// k_proj: QKV projection GEMM. grid (144,3) x 256. Tile 64 rows x 64 cols.
// Epilogue also writes bf16 hi/lo splits of q,k and transposed bf16 V.
// ---------------------------------------------------------------------------
__global__ __launch_bounds__(256) void k_proj(
    const float* __restrict__ xn,
    const float* __restrict__ Wq,  const float* __restrict__ Wk,  const float* __restrict__ Wv,
    const float* __restrict__ Wqs, const float* __restrict__ Wks, const float* __restrict__ Wvs,
    const float* __restrict__ Wqe, const float* __restrict__ Wke, const float* __restrict__ Wve,
    float* __restrict__ qf, float* __restrict__ kf, float* __restrict__ vf,
    unsigned short* __restrict__ qsp, unsigned short* __restrict__ ksp,
    unsigned short* __restrict__ vbfT)
{
    __shared__ float xs[64 * 68];
    __shared__ float ws_[64 * 68];
    const int tid  = threadIdx.x;
    const int row0 = blockIdx.x * 64;
    const int rseq = row0 % L_;
    const int seg  = (rseq < S_) ? 0 : (rseq >= L_ - S_) ? 2 : 1;
    const int m    = blockIdx.y;
    const float* W;
    float* out;
    if (m == 0)      { W = (seg == 0) ? Wqs : (seg == 2) ? Wqe : Wq; out = qf; }
    else if (m == 1) { W = (seg == 0) ? Wks : (seg == 2) ? Wke : Wk; out = kf; }
    else             { W = (seg == 0) ? Wvs : (seg == 2) ? Wve : Wv; out = vf; }

    const int c4 = tid & 15, r4 = tid >> 4;
    float acc[4][4] = {};

    for (int kc = 0; kc < DIN; kc += 64) {
        __syncthreads();
        #pragma unroll
        for (int i = 0; i < 4; ++i) {
            int g = tid + 256 * i;
            int r = g >> 4, f = g & 15;
            *(float4*)(xs + r * 68 + f * 4) =
                ((const float4*)xn)[(size_t)(row0 + r) * (DIN / 4) + kc / 4 + f];
        }
        #pragma unroll
        for (int i = 0; i < 4; ++i) {
            int g = tid + 256 * i;
            int k = g >> 4, f = g & 15;
            *(float4*)(ws_ + k * 68 + f * 4) =
                ((const float4*)W)[(size_t)(kc + k) * (DK / 4) + f];
        }
        __syncthreads();
        #pragma unroll 4
        for (int k = 0; k < 64; ++k) {
            float4 wv = *(const float4*)(ws_ + k * 68 + c4 * 4);
            #pragma unroll
            for (int i = 0; i < 4; ++i) {
                float a = xs[(r4 * 4 + i) * 68 + k];
                acc[i][0] += a * wv.x; acc[i][1] += a * wv.y;
                acc[i][2] += a * wv.z; acc[i][3] += a * wv.w;
            }
        }
    }
    const int bI = row0 / L_;
    const int rb = row0 - bI * L_;
    #pragma unroll
    for (int i = 0; i < 4; ++i) {
        float4 o = make_float4(acc[i][0], acc[i][1], acc[i][2], acc[i][3]);
        *(float4*)(out + (size_t)(row0 + r4 * 4 + i) * DK + c4 * 4) = o;
    }
    if (m < 2) {
        unsigned short* sp = (m == 0) ? qsp : ksp;
        #pragma unroll
        for (int i = 0; i < 4; ++i) {
            size_t rg = (size_t)(row0 + r4 * 4 + i);
            unsigned short hs[4], ls[4];
            #pragma unroll
            for (int j = 0; j < 4; ++j) {
                float v = acc[i][j];
                unsigned short h = f2bf(v);
                hs[j] = h;
                ls[j] = f2bf(v - bf2f(h));
            }
            *(uint2*)(sp + rg * 128 + c4 * 4)       = *(uint2*)hs;
            *(uint2*)(sp + rg * 128 + 64 + c4 * 4)  = *(uint2*)ls;
        }
    } else {
        #pragma unroll
        for (int i = 0; i < 4; ++i) {
            int rr = rb + r4 * 4 + i;
            #pragma unroll
            for (int j = 0; j < 4; ++j)
                vbfT[(size_t)(bI * 64 + c4 * 4 + j) * L_ + rr] = f2bf(acc[i][j]);
        }
    }
}

// ---------------------------------------------------------------------------
// k_cope: Li[gr][p] = q_mid[gr] . cope[:,p]. grid 256 x 256.
// ---------------------------------------------------------------------------
__global__ __launch_bounds__(256) void k_cope(
    const float* __restrict__ qf, const float* __restrict__ cope,
    float* __restrict__ Li)
{
    __shared__ float qs[32 * 68];
    const int tid = threadIdx.x;
    const int gr0 = blockIdx.x * 32;
    const int b   = gr0 >> 11;
    const size_t qrow0 = (size_t)b * L_ + S_ + (gr0 & 2047);
    #pragma unroll
    for (int i = 0; i < 2; ++i) {
        int g = tid + 256 * i;
        int r = g >> 4, f = g & 15;
        *(float4*)(qs + r * 68 + f * 4) = ((const float4*)qf)[(qrow0 + r) * 16 + f];
    }
    __syncthreads();
    const int c4 = tid & 31, r4 = tid >> 5;
    float acc[4][4] = {};
    for (int d = 0; d < DK; ++d) {
        float4 cv = ((const float4*)cope)[d * 32 + c4];
        #pragma unroll
        for (int i = 0; i < 4; ++i) {
            float a = qs[(r4 * 4 + i) * 68 + d];
            acc[i][0] += a * cv.x; acc[i][1] += a * cv.y;
            acc[i][2] += a * cv.z; acc[i][3] += a * cv.w;
        }
    }
    #pragma unroll
    for (int i = 0; i < 4; ++i)
        *(float4*)(Li + (size_t)(gr0 + r4 * 4 + i) * 128 + c4 * 4) =
            make_float4(acc[i][0], acc[i][1], acc[i][2], acc[i][3]);
}

// ---------------------------------------------------------------------------
// k_dots: D = Qmid . K^T via split-bf16 MFMA. grid (64, 34) x 256.
// Tile 128 q-rows x 64 cols. Split product: qh*kh + qh*kl + ql*kh.
// ---------------------------------------------------------------------------
__global__ __launch_bounds__(256) void k_dots(
    const unsigned short* __restrict__ qsp, const unsigned short* __restrict__ ksp,
    float* __restrict__ D)
{
    __shared__ short Qs[128 * 136];   // [row][hi 0..63 | lo 64..127 | pad]
    __shared__ short Ks[64 * 136];
    const int tid  = threadIdx.x;
    const int gr0  = blockIdx.x * 128;
    const int col0 = blockIdx.y * 64;
    const int b    = gr0 >> 11;
    const size_t qrow0 = (size_t)b * L_ + S_ + (gr0 & 2047);
    const size_t krow0 = (size_t)b * L_ + col0;

    #pragma unroll
    for (int i = 0; i < 8; ++i) {
        int g = tid + 256 * i;           // 128 rows x 16 x 16B
        int r = g >> 4, c = g & 15;
        *(uint4*)(Qs + r * 136 + c * 8) = ((const uint4*)qsp)[(qrow0 + r) * 16 + c];
    }
    #pragma unroll
    for (int i = 0; i < 4; ++i) {
        int g = tid + 256 * i;           // 64 rows x 16 x 16B
        int r = g >> 4, c = g & 15;
        *(uint4*)(Ks + r * 136 + c * 8) = ((const uint4*)ksp)[(krow0 + r) * 16 + c];
    }
    __syncthreads();

    const int w = tid >> 6, lane = tid & 63;
    const int cl = lane & 15, quad = lane >> 4;

    f32x4 acc[2][4];
    #pragma unroll
    for (int i = 0; i < 2; ++i)
        #pragma unroll
        for (int j = 0; j < 4; ++j) acc[i][j] = 0.f;

    #pragma unroll
    for (int h = 0; h < 2; ++h) {
        short8 ah[2], al[2], bh[4], bl[4];
        #pragma unroll
        for (int rs = 0; rs < 2; ++rs) {
            const short* base = Qs + (32 * w + 16 * rs + cl) * 136 + h * 32 + quad * 8;
            ah[rs] = *(const short8*)(base);
            al[rs] = *(const short8*)(base + 64);
        }
        #pragma unroll
        for (int c = 0; c < 4; ++c) {
            const short* base = Ks + (16 * c + cl) * 136 + h * 32 + quad * 8;
            bh[c] = *(const short8*)(base);
            bl[c] = *(const short8*)(base + 64);
        }
        #pragma unroll
        for (int rs = 0; rs < 2; ++rs)
            #pragma unroll
            for (int c = 0; c < 4; ++c) {
                acc[rs][c] = __builtin_amdgcn_mfma_f32_16x16x32_bf16(ah[rs], bh[c], acc[rs][c], 0, 0, 0);
                acc[rs][c] = __builtin_amdgcn_mfma_f32_16x16x32_bf16(ah[rs], bl[c], acc[rs][c], 0, 0, 0);
                acc[rs][c] = __builtin_amdgcn_mfma_f32_16x16x32_bf16(al[rs], bh[c], acc[rs][c], 0, 0, 0);
            }
    }

    #pragma unroll
    for (int rs = 0; rs < 2; ++rs)
        #pragma unroll
        for (int c = 0; c < 4; ++c)
            #pragma unroll
            for (int r = 0; r < 4; ++r) {
                int mrow = gr0 + 32 * w + 16 * rs + quad * 4 + r;
                int n    = col0 + 16 * c + cl;
                D[(size_t)mrow * NCOLS + n] = acc[rs][c][r];
            }
}

// ---------------------------------------------------------------------------
// k_scan: gates -> suffix scan -> CoPE bias -> softmax; writes normalized P
// as bf16 in place over the head of its own D row. grid 8192 x 256.
// ---------------------------------------------------------------------------
__global__ __launch_bounds__(256) void k_scan(
    const float* __restrict__ Li, float* __restrict__ D)
{
    __shared__ float ds[NCOLS];
    __shared__ float li[128];
    __shared__ float red[256];
    __shared__ float wtot[4];
    const int tid = threadIdx.x;
    const int gr  = blockIdx.x;
    const int q   = gr & 2047;
    const size_t rowoff = (size_t)gr * NCOLS;

    for (int g = tid; g < NCOLS / 4; g += 256)
        ((float4*)ds)[g] = ((const float4*)(D + rowoff))[g];
    if (tid < 32) ((float4*)li)[tid] = ((const float4*)(Li + (size_t)gr * 128))[tid];
    __syncthreads();

    const int j0 = tid * 8;
    float dot[8], gte[8];
    *(float4*)&dot[0] = *(const float4*)(ds + 128 + j0);
    *(float4*)&dot[4] = *(const float4*)(ds + 128 + j0 + 4);
    float csum = 0.f;
    #pragma unroll
    for (int jj = 0; jj < 8; ++jj) {
        gte[jj] = 1.f / (1.f + __expf(-dot[jj]));
        csum += gte[jj];
    }
    const int lane = tid & 63, wid = tid >> 6;
    float inc = csum;
    #pragma unroll
    for (int off = 1; off < 64; off <<= 1) {
        float u = __shfl_down(inc, off, 64);
        if (lane + off < 64) inc += u;
    }
    if (lane == 0) wtot[wid] = inc;
    __syncthreads();
    float wsuf = 0.f;
    #pragma unroll
    for (int w = 0; w < 4; ++w) if (w > wid) wsuf += wtot[w];
    float run = inc - csum + wsuf;

    float p8[8];
    #pragma unroll
    for (int jj = 7; jj >= 0; --jj) {
        run += gte[jj];
        float pos = fminf(run, (float)(S_ - 1));
        float pfl = floorf(pos);
        int ic  = (int)ceilf(pos);
        int ifl = (int)pfl;
        float w = pos - pfl;
        float bias = li[ic] * w + li[ifl] * (1.f - w);
        p8[jj] = (j0 + jj <= q) ? dot[jj] * SCALE + bias : NEGINF;
    }
    float sv = (tid < 128) ? ds[tid] * SCALE : NEGINF;

    float mx = sv;
    #pragma unroll
    for (int jj = 0; jj < 8; ++jj) mx = fmaxf(mx, p8[jj]);
    red[tid] = mx;
    __syncthreads();
    for (int off = 128; off > 0; off >>= 1) {
        if (tid < off) red[tid] = fmaxf(red[tid], red[tid + off]);
        __syncthreads();
    }
    mx = red[0];
    __syncthreads();

    float lsum = 0.f;
    float e8[8];
    #pragma unroll
    for (int jj = 0; jj < 8; ++jj) {
        e8[jj] = __expf(p8[jj] - mx);
        lsum += e8[jj];
    }
    float es = 0.f;
    if (tid < 128) { es = __expf(sv - mx); lsum += es; }
    red[tid] = lsum;
    __syncthreads();
    for (int off = 128; off > 0; off >>= 1) {
        if (tid < off) red[tid] += red[tid + off];
        __syncthreads();
    }
    float inv = 1.f / red[0];

    unsigned short* pb = (unsigned short*)D + (size_t)gr * PROWS;
    union { unsigned short s[8]; uint4 v; } pk;
    #pragma unroll
    for (int jj = 0; jj < 8; ++jj) pk.s[jj] = f2bf(e8[jj] * inv);
    *(uint4*)(pb + 128 + j0) = pk.v;
    if (tid < 128) pb[tid] = f2bf(es * inv);
}

// ---------------------------------------------------------------------------
// k_pv: O = P(bf16) @ V(bf16, transposed layout) via MFMA, 4-way K-split.
// grid (128, 4) x 256. Tile 64 q-rows x 64 dims, chunk 64 keys.
// ---------------------------------------------------------------------------
__global__ __launch_bounds__(256) void k_pv(
    const unsigned short* __restrict__ Pb, const unsigned short* __restrict__ vbfT,
    float* __restrict__ Opart)
{
    __shared__ short Ps[64 * 72];   // [q-row][key]
    __shared__ short Vt[64 * 72];   // [dim][key]
    const int tid = threadIdx.x;
    const int gr0 = blockIdx.x * 64;
    const int ks  = blockIdx.y;
    const int b   = gr0 >> 11, q0 = gr0 & 2047;
    const int cmax  = (191 + q0) >> 6;
    const int c_beg = ks * 9;
    int c_end = c_beg + 9;
    if (c_end > 34) c_end = 34;
    if (c_end > cmax + 1) c_end = cmax + 1;

    const int w = tid >> 6, lane = tid & 63;
    const int cl = lane & 15, quad = lane >> 4;
    f32x4 acc[4];
    #pragma unroll
    for (int c = 0; c < 4; ++c) acc[c] = 0.f;

    for (int ch = c_beg; ch < c_end; ++ch) {
        __syncthreads();
        #pragma unroll
        for (int i = 0; i < 2; ++i) {
            int g = tid + 256 * i;       // 64 rows x 8 x 16B
            int r = g >> 3, c = g & 7;
            *(uint4*)(Ps + r * 72 + c * 8) =
                *(const uint4*)(Pb + (size_t)(gr0 + r) * PROWS + ch * 64 + c * 8);
        }
        #pragma unroll
        for (int i = 0; i < 2; ++i) {
            int g = tid + 256 * i;       // 64 dims x 8 x 16B
            int r = g >> 3, c = g & 7;
            *(uint4*)(Vt + r * 72 + c * 8) =
                *(const uint4*)(vbfT + (size_t)(b * 64 + r) * L_ + ch * 64 + c * 8);
        }
        __syncthreads();
        #pragma unroll
        for (int h = 0; h < 2; ++h) {
            short8 a = *(const short8*)(Ps + (16 * w + cl) * 72 + h * 32 + quad * 8);
            #pragma unroll
            for (int c = 0; c < 4; ++c) {
                short8 bv = *(const short8*)(Vt + (16 * c + cl) * 72 + h * 32 + quad * 8);
                acc[c] = __builtin_amdgcn_mfma_f32_16x16x32_bf16(a, bv, acc[c], 0, 0, 0);
            }
        }
    }
    #pragma unroll
    for (int c = 0; c < 4; ++c)
        #pragma unroll
        for (int r = 0; r < 4; ++r) {
            int mrow = gr0 + 16 * w + quad * 4 + r;
            int n    = 16 * c + cl;
            Opart[((size_t)ks * NMID + mrow) * DK + n] = acc[c][r];
        }
}

// ---------------------------------------------------------------------------
// k_merge: out(mid rows) = sum of 4 partials. grid 2048 x 256.
// ---------------------------------------------------------------------------
__global__ __launch_bounds__(256) void k_merge(
    const float* __restrict__ Opart, float* __restrict__ out)
{
    const int e  = blockIdx.x * 256 + threadIdx.x;
    const int gr = e >> 6, c = e & 63;
    const int b  = gr >> 11, q = gr & 2047;
    const int NP = NMID * DK;
    float s = Opart[e] + Opart[e + NP] + Opart[e + 2 * NP] + Opart[e + 3 * NP];
    out[((size_t)b * L_ + S_ + q) * DK + c] = s;
}

// ---------------------------------------------------------------------------
// k_dots_edge: De[er][col] = q_edge[er] . k[col]. grid (8,18) x 256.
// ---------------------------------------------------------------------------
__global__ __launch_bounds__(256) void k_dots_edge(
    const float* __restrict__ qf, const float* __restrict__ kf,
    float* __restrict__ De)
{
    const int bx   = blockIdx.x;
    const int b    = bx >> 1;
    const int half = bx & 1;
    const int col0 = blockIdx.y * 128;
    if (half == 0 && col0 > 127) return;

    __shared__ float Qs[128 * 68];
    __shared__ float Kt[64 * 136];
    const int tid = threadIdx.x;
    const int er0 = bx * 128;
    const size_t qrow0 = (size_t)b * L_ + (half ? 2176 : 0);
    const size_t krow0 = (size_t)b * L_ + col0;

    #pragma unroll
    for (int i = 0; i < 8; ++i) {
        int g = tid + 256 * i;
        int r = g >> 4, f = g & 15;
        *(float4*)(Qs + r * 68 + f * 4) = ((const float4*)qf)[(qrow0 + r) * 16 + f];
    }
    #pragma unroll
    for (int i = 0; i < 8; ++i) {
        int g = tid + 256 * i;
        int j = g >> 4, f = g & 15;
        float4 kv = ((const float4*)kf)[(krow0 + j) * 16 + f];
        Kt[(f * 4 + 0) * 136 + j] = kv.x;
        Kt[(f * 4 + 1) * 136 + j] = kv.y;
        Kt[(f * 4 + 2) * 136 + j] = kv.z;
        Kt[(f * 4 + 3) * 136 + j] = kv.w;
    }
    __syncthreads();

    const int c8 = tid & 15, r8 = tid >> 4;
    float acc[8][8] = {};
    for (int d0 = 0; d0 < 64; d0 += 4) {
        float4 a[8];
        #pragma unroll
        for (int i = 0; i < 8; ++i)
            a[i] = *(const float4*)(Qs + (r8 * 8 + i) * 68 + d0);
        #pragma unroll
        for (int dd = 0; dd < 4; ++dd) {
            float4 k0 = *(const float4*)(Kt + (d0 + dd) * 136 + c8 * 8);
            float4 k1 = *(const float4*)(Kt + (d0 + dd) * 136 + c8 * 8 + 4);
            #pragma unroll
            for (int i = 0; i < 8; ++i) {
                float av = (dd == 0) ? a[i].x : (dd == 1) ? a[i].y : (dd == 2) ? a[i].z : a[i].w;
                acc[i][0] += av * k0.x; acc[i][1] += av * k0.y;
                acc[i][2] += av * k0.z; acc[i][3] += av * k0.w;
                acc[i][4] += av * k1.x; acc[i][5] += av * k1.y;
                acc[i][6] += av * k1.z; acc[i][7] += av * k1.w;
            }
        }
    }
    #pragma unroll
    for (int i = 0; i < 8; ++i) {
        size_t o = (size_t)(er0 + r8 * 8 + i) * LE + col0 + c8 * 8;
        *(float4*)(De + o)     = make_float4(acc[i][0], acc[i][1], acc[i][2], acc[i][3]);
        *(float4*)(De + o + 4) = make_float4(acc[i][4], acc[i][5], acc[i][6], acc[i][7]);
    }
}

// ---------------------------------------------------------------------------
// k_soft_edge: row-wise causal softmax on De. grid 1024 x 256.
// ---------------------------------------------------------------------------
__global__ __launch_bounds__(256) void k_soft_edge(float* __restrict__ De)
{
    __shared__ float red[256];
    const int tid = threadIdx.x;
    const int er  = blockIdx.x;
    const int r   = er & 255;
    const int Q   = (r < 128) ? r : (2048 + r);
    const size_t rowoff = (size_t)er * LE;

    float v[9];
    #pragma unroll
    for (int i = 0; i < 9; ++i) {
        int j = tid + 256 * i;
        float d = De[rowoff + j];
        v[i] = (j <= Q) ? d * SCALE : NEGINF;
    }
    float mx = v[0];
    #pragma unroll
    for (int i = 1; i < 9; ++i) mx = fmaxf(mx, v[i]);
    red[tid] = mx;
    __syncthreads();
    for (int off = 128; off > 0; off >>= 1) {
        if (tid < off) red[tid] = fmaxf(red[tid], red[tid + off]);
        __syncthreads();
    }
    mx = red[0];
    __syncthreads();

    float lsum = 0.f;
    #pragma unroll
    for (int i = 0; i < 9; ++i) {
        v[i] = __expf(v[i] - mx);
        lsum += v[i];
    }
    red[tid] = lsum;
    __syncthreads();
    for (int off = 128; off > 0; off >>= 1) {
        if (tid < off) red[tid] += red[tid + off];
        __syncthreads();
    }
    float inv = 1.f / red[0];
    #pragma unroll
    for (int i = 0; i < 9; ++i)
        De[rowoff + tid + 256 * i] = v[i] * inv;
}

// ---------------------------------------------------------------------------
// k_pv_edge: partial Oe = Pe @ V, 4-way K-split over 36 chunks. grid (32,4).
// ---------------------------------------------------------------------------
__global__ __launch_bounds__(256) void k_pv_edge(
    const float* __restrict__ De, const float* __restrict__ vf,
    float* __restrict__ Oe)
{
    __shared__ float Ps[32 * 68];
    __shared__ float Vs[64 * 68];
    const int tid = threadIdx.x;
    const int er0 = blockIdx.x * 32;
    const int ks  = blockIdx.y;
    const int b   = er0 >> 8, r0 = er0 & 255;
    const int Qmax = (r0 < 128) ? (r0 + 31) : (2048 + r0 + 31);
    const int cmax = Qmax >> 6;
    const int c_beg = ks * 9;
    int c_end = c_beg + 9;
    if (c_end > 36) c_end = 36;
    if (c_end > cmax + 1) c_end = cmax + 1;

    const int c4 = tid & 15, rg = tid >> 4;
    float acc[2][4] = {};

    for (int ch = c_beg; ch < c_end; ++ch) {
        __syncthreads();
        #pragma unroll
        for (int i = 0; i < 2; ++i) {
            int g = tid + 256 * i;
            int r = g >> 4, f = g & 15;
            *(float4*)(Ps + r * 68 + f * 4) =
                *(const float4*)(De + (size_t)(er0 + r) * LE + ch * 64 + f * 4);
        }
        #pragma unroll
        for (int i = 0; i < 4; ++i) {
            int g = tid + 256 * i;
            int j = g >> 4, f = g & 15;
            *(float4*)(Vs + j * 68 + f * 4) =
                *(const float4*)(vf + (size_t)(b * L_ + ch * 64 + j) * DK + f * 4);
        }
        __syncthreads();
        #pragma unroll 4
        for (int j = 0; j < 64; ++j) {
            float4 vv = *(const float4*)(Vs + j * 68 + c4 * 4);
            float p0 = Ps[(rg * 2 + 0) * 68 + j];
            float p1 = Ps[(rg * 2 + 1) * 68 + j];
            acc[0][0] += p0 * vv.x; acc[0][1] += p0 * vv.y;
            acc[0][2] += p0 * vv.z; acc[0][3] += p0 * vv.w;
            acc[1][0] += p1 * vv.x; acc[1][1] += p1 * vv.y;
            acc[1][2] += p1 * vv.z; acc[1][3] += p1 * vv.w;
        }
    }
    #pragma unroll
    for (int i = 0; i < 2; ++i)
        *(float4*)(Oe + ((size_t)ks * NEDGE + er0 + rg * 2 + i) * DK + c4 * 4) =
            make_float4(acc[i][0], acc[i][1], acc[i][2], acc[i][3]);
}

// ---------------------------------------------------------------------------
// k_merge_edge: out(edge rows) = sum of 4 partials. grid 256 x 256.
// ---------------------------------------------------------------------------
__global__ __launch_bounds__(256) void k_merge_edge(
    const float* __restrict__ Oe, float* __restrict__ out)
{
    const int e  = blockIdx.x * 256 + threadIdx.x;
    const int er = e >> 6, c = e & 63;
    const int b  = er >> 8, r = er & 255;
    const int gQ = (r < 128) ? r : (2048 + r);
    const int NP = NEDGE * DK;
    float s = Oe[e] + Oe[e + NP] + Oe[e + 2 * NP] + Oe[e + 3 * NP];
    out[((size_t)b * L_ + gQ) * DK + c] = s;
}

// ---------------------------------------------------------------------------
extern "C" void kernel_launch(void* const* d_in, const int* in_sizes, int n_in,
                              void* d_out, int out_size, void* d_ws, size_t ws_size,
                              hipStream_t stream)
{
    const float* x    = (const float*)d_in[0];
    const float* Wq   = (const float*)d_in[1];
    const float* Wk   = (const float*)d_in[2];
    const float* Wv   = (const float*)d_in[3];
    const float* Wqs  = (const float*)d_in[4];
    const float* Wks  = (const float*)d_in[5];
    const float* Wvs  = (const float*)d_in[6];
    const float* Wqe  = (const float*)d_in[7];
    const float* Wke  = (const float*)d_in[8];
    const float* Wve  = (const float*)d_in[9];
    const float* g0   = (const float*)d_in[10];
    const float* b0   = (const float*)d_in[11];
    const float* gs   = (const float*)d_in[12];
    const float* bs   = (const float*)d_in[13];
    const float* ge   = (const float*)d_in[14];
    const float* be   = (const float*)d_in[15];
    const float* cope = (const float*)d_in[16];

    float* ws = (float*)d_ws;
    float* qf    = ws;                               // 9216*64 f32
    float* kf    = qf + (size_t)9216 * DK;
    float* vf    = kf + (size_t)9216 * DK;
    float* Li    = vf + (size_t)9216 * DK;           // 8192*128 f32 (dead after scan)
    float* Opart = Li + (size_t)NMID * 128;          // 4*8192*64 f32
    unsigned short* qsp  = (unsigned short*)(Opart + (size_t)4 * NMID * DK); // 9216*128 bf16
    unsigned short* ksp  = qsp + (size_t)9216 * 128;
    unsigned short* vbfT = ksp + (size_t)9216 * 128;                         // 4*64*2304 bf16
    float* xn    = (float*)(vbfT + (size_t)4 * 64 * L_);  // 9216*512 (dead after proj)
    float* D     = xn;                               // 8192*2176 f32 overlaps xn
    float* De    = D;                                // edge reuses D after k_pv
    float* Oe    = Li;                               // edge reuses Li
    float* out   = (float*)d_out;

    k_ln  <<<L_ * B_ / 4, 256, 0, stream>>>(x, g0, b0, gs, bs, ge, be, xn);
    k_proj<<<dim3(144, 3), 256, 0, stream>>>(xn, Wq, Wk, Wv, Wqs, Wks, Wvs,
                                             Wqe, Wke, Wve, qf, kf, vf,
                                             qsp, ksp, vbfT);
    k_cope<<<NMID / 32, 256, 0, stream>>>(qf, cope, Li);
    k_dots<<<dim3(NMID / 128, NCOLS / 64), 256, 0, stream>>>(qsp, ksp, D);
    k_scan<<<NMID, 256, 0, stream>>>(Li, D);
    k_pv  <<<dim3(NMID / 64, 4), 256, 0, stream>>>((const unsigned short*)D, vbfT, Opart);
    k_merge<<<NMID * DK / 256, 256, 0, stream>>>(Opart, out);
    // edge path (reuses D's memory after k_pv)
    k_dots_edge<<<dim3(8, 18), 256, 0, stream>>>(qf, kf, De);
    k_soft_edge<<<NEDGE, 256, 0, stream>>>(De);
    k_pv_edge<<<dim3(NEDGE / 32, 4), 256, 0, stream>>>(De, vf, Oe);
    k_merge_edge<<<NEDGE * DK / 256, 256, 0, stream>>>(Oe, out);
}

// Round 8
// 230.605 us; speedup vs baseline: 6.8512x; 1.0473x over previous
//
#include <hip/hip_runtime.h>
#include <math.h>

#define B_    4
#define SEQ_  2048
#define S_    128
#define L_    2304          // SEQ + 2*S
#define DIN   512
#define DK    64
#define NEGINF (-1e30f)
#define SCALE 0.125f
#define NCOLS 2176          // start(128) + mid(2048) key columns in D
#define NMID  8192          // B_*SEQ_
#define NEDGE 1024          // B_*2*S_
#define LE    2304          // edge D row length
#define PROWS 4352          // fp16 pitch inside an fp32 D row (NCOLS*2 halves)

typedef _Float16 f16;
typedef __attribute__((ext_vector_type(8))) _Float16 half8;
typedef __attribute__((ext_vector_type(4))) float f32x4;

union U4 { uint4 u; f16 h[8]; };

// ---------------------------------------------------------------------------
// k_ln: wave-per-row LayerNorm, writes hi/lo fp16 split of xn.
// grid 2304 x 256 (4 rows/blk).
// ---------------------------------------------------------------------------
__global__ __launch_bounds__(256) void k_ln(
    const float* __restrict__ x,
    const float* __restrict__ g0, const float* __restrict__ b0,
    const float* __restrict__ gs, const float* __restrict__ bs,
    const float* __restrict__ ge, const float* __restrict__ be,
    f16* __restrict__ xh, f16* __restrict__ xl)
{
    const int wave = threadIdx.x >> 6, lane = threadIdx.x & 63;
    const int row  = blockIdx.x * 4 + wave;
    const float4* xr = (const float4*)(x + (size_t)row * DIN);
    float4 v0 = xr[lane], v1 = xr[lane + 64];
    float s  = v0.x + v0.y + v0.z + v0.w + v1.x + v1.y + v1.z + v1.w;
    float s2 = v0.x*v0.x + v0.y*v0.y + v0.z*v0.z + v0.w*v0.w
             + v1.x*v1.x + v1.y*v1.y + v1.z*v1.z + v1.w*v1.w;
    #pragma unroll
    for (int m = 1; m < 64; m <<= 1) { s += __shfl_xor(s, m); s2 += __shfl_xor(s2, m); }
    float mean = s * (1.f / DIN);
    float var  = s2 * (1.f / DIN) - mean * mean;
    float rstd = rsqrtf(var + 1e-5f);

    const int r = row % L_;
    const float *gg, *bb;
    if (r < S_)            { gg = gs; bb = bs; }
    else if (r >= L_ - S_) { gg = ge; bb = be; }
    else                   { gg = g0; bb = b0; }
    float4 ga = ((const float4*)gg)[lane], gb = ((const float4*)gg)[lane + 64];
    float4 ba = ((const float4*)bb)[lane], bb4 = ((const float4*)bb)[lane + 64];

    float n0[4], n1[4];
    n0[0] = (v0.x - mean) * rstd * ga.x + ba.x;
    n0[1] = (v0.y - mean) * rstd * ga.y + ba.y;
    n0[2] = (v0.z - mean) * rstd * ga.z + ba.z;
    n0[3] = (v0.w - mean) * rstd * ga.w + ba.w;
    n1[0] = (v1.x - mean) * rstd * gb.x + bb4.x;
    n1[1] = (v1.y - mean) * rstd * gb.y + bb4.y;
    n1[2] = (v1.z - mean) * rstd * gb.z + bb4.z;
    n1[3] = (v1.w - mean) * rstd * gb.w + bb4.w;

    union { uint2 u; f16 h[4]; } h0, h1, l0, l1;
    #pragma unroll
    for (int i = 0; i < 4; ++i) {
        h0.h[i] = (f16)n0[i]; l0.h[i] = (f16)(n0[i] - (float)h0.h[i]);
        h1.h[i] = (f16)n1[i]; l1.h[i] = (f16)(n1[i] - (float)h1.h[i]);
    }
    f16* ph = xh + (size_t)row * DIN;
    f16* pl = xl + (size_t)row * DIN;
    *(uint2*)(ph + 4 * lane)       = h0.u;
    *(uint2*)(ph + 256 + 4 * lane) = h1.u;
    *(uint2*)(pl + 4 * lane)       = l0.u;
    *(uint2*)(pl + 256 + 4 * lane) = l1.u;
}

// ---------------------------------------------------------------------------
// k_proj: QKV projection via split-fp16 MFMA (3 terms for q,k; 1 for v).
// grid (144,3) x 256. Tile 64x64.  Emits f32 q/k/v, split-fp16 q/k,
// transposed fp16 V.
// ---------------------------------------------------------------------------
__global__ __launch_bounds__(256) void k_proj(
    const f16* __restrict__ xh, const f16* __restrict__ xl,
    const float* __restrict__ Wq,  const float* __restrict__ Wk,  const float* __restrict__ Wv,
    const float* __restrict__ Wqs, const float* __restrict__ Wks, const float* __restrict__ Wvs,
    const float* __restrict__ Wqe, const float* __restrict__ Wke, const float* __restrict__ Wve,
    float* __restrict__ qf, float* __restrict__ kf, float* __restrict__ vf,
    f16* __restrict__ qsp, f16* __restrict__ ksp, f16* __restrict__ vhT)
{
    __shared__ f16 As[64 * 136];   // [row][hi 0..63 | lo 64..127 | pad]
    __shared__ f16 Bs[64 * 136];   // [col][hi k | lo k]
    const int tid  = threadIdx.x;
    const int row0 = blockIdx.x * 64;
    const int rseq = row0 % L_;
    const int seg  = (rseq < S_) ? 0 : (rseq >= L_ - S_) ? 2 : 1;
    const int m    = blockIdx.y;
    const float* W;
    float* outf;
    if (m == 0)      { W = (seg == 0) ? Wqs : (seg == 2) ? Wqe : Wq; outf = qf; }
    else if (m == 1) { W = (seg == 0) ? Wks : (seg == 2) ? Wke : Wk; outf = kf; }
    else             { W = (seg == 0) ? Wvs : (seg == 2) ? Wve : Wv; outf = vf; }

    const int w = tid >> 6, lane = tid & 63;
    const int cl = lane & 15, quad = lane >> 4;
    const int r0 = 32 * (w >> 1), c0 = 32 * (w & 1);

    f32x4 acc[2][2];
    #pragma unroll
    for (int i = 0; i < 2; ++i)
        #pragma unroll
        for (int j = 0; j < 2; ++j) acc[i][j] = 0.f;

    for (int kc = 0; kc < DIN; kc += 64) {
        __syncthreads();
        #pragma unroll
        for (int i = 0; i < 2; ++i) {
            int g = tid + 256 * i;               // 0..511: 64 rows x 8 uint4
            int r = g >> 3, c = g & 7;
            *(uint4*)(As + r * 136 + c * 8) =
                *(const uint4*)(xh + (size_t)(row0 + r) * DIN + kc + c * 8);
            *(uint4*)(As + r * 136 + 64 + c * 8) =
                *(const uint4*)(xl + (size_t)(row0 + r) * DIN + kc + c * 8);
        }
        #pragma unroll
        for (int i = 0; i < 4; ++i) {
            int g = tid + 256 * i;               // 64 k x 16 float4
            int k = g >> 4, c4 = g & 15;
            float4 wv = ((const float4*)W)[(size_t)(kc + k) * 16 + c4];
            f16 h0 = (f16)wv.x, h1 = (f16)wv.y, h2 = (f16)wv.z, h3 = (f16)wv.w;
            Bs[(c4 * 4 + 0) * 136 + k] = h0;
            Bs[(c4 * 4 + 1) * 136 + k] = h1;
            Bs[(c4 * 4 + 2) * 136 + k] = h2;
            Bs[(c4 * 4 + 3) * 136 + k] = h3;
            Bs[(c4 * 4 + 0) * 136 + 64 + k] = (f16)(wv.x - (float)h0);
            Bs[(c4 * 4 + 1) * 136 + 64 + k] = (f16)(wv.y - (float)h1);
            Bs[(c4 * 4 + 2) * 136 + 64 + k] = (f16)(wv.z - (float)h2);
            Bs[(c4 * 4 + 3) * 136 + 64 + k] = (f16)(wv.w - (float)h3);
        }
        __syncthreads();
        #pragma unroll
        for (int h = 0; h < 2; ++h) {
            half8 ah[2], al[2], bh[2], bl[2];
            #pragma unroll
            for (int rs = 0; rs < 2; ++rs) {
                const f16* base = As + (r0 + 16 * rs + cl) * 136 + h * 32 + quad * 8;
                ah[rs] = *(const half8*)(base);
                al[rs] = *(const half8*)(base + 64);
            }
            #pragma unroll
            for (int cs = 0; cs < 2; ++cs) {
                const f16* base = Bs + (c0 + 16 * cs + cl) * 136 + h * 32 + quad * 8;
                bh[cs] = *(const half8*)(base);
                bl[cs] = *(const half8*)(base + 64);
            }
            #pragma unroll
            for (int rs = 0; rs < 2; ++rs)
                #pragma unroll
                for (int cs = 0; cs < 2; ++cs) {
                    acc[rs][cs] = __builtin_amdgcn_mfma_f32_16x16x32_f16(ah[rs], bh[cs], acc[rs][cs], 0, 0, 0);
                    if (m < 2) {
                        acc[rs][cs] = __builtin_amdgcn_mfma_f32_16x16x32_f16(ah[rs], bl[cs], acc[rs][cs], 0, 0, 0);
                        acc[rs][cs] = __builtin_amdgcn_mfma_f32_16x16x32_f16(al[rs], bh[cs], acc[rs][cs], 0, 0, 0);
                    }
                }
        }
    }

    const int bI = row0 / L_;
    const int rb = row0 - bI * L_;
    f16* sp = (m == 0) ? qsp : ksp;
    #pragma unroll
    for (int rs = 0; rs < 2; ++rs)
        #pragma unroll
        for (int cs = 0; cs < 2; ++cs)
            #pragma unroll
            for (int r = 0; r < 4; ++r) {
                int lrow = r0 + 16 * rs + quad * 4 + r;
                int col  = c0 + 16 * cs + cl;
                float v  = acc[rs][cs][r];
                size_t grow = (size_t)(row0 + lrow);
                outf[grow * DK + col] = v;
                if (m < 2) {
                    f16 hv = (f16)v;
                    sp[grow * 128 + col]      = hv;
                    sp[grow * 128 + 64 + col] = (f16)(v - (float)hv);
                } else {
                    vhT[(size_t)(bI * 64 + col) * L_ + rb + lrow] = (f16)v;
                }
            }
}

// ---------------------------------------------------------------------------
// k_dots: D(fp32) = Qmid . K^T via split-fp16 MFMA (3 terms).
// grid (64, 34) x 256. Tile 128 q-rows x 64 key-cols.
// ---------------------------------------------------------------------------
__global__ __launch_bounds__(256) void k_dots(
    const f16* __restrict__ qsp, const f16* __restrict__ ksp,
    float* __restrict__ D)
{
    __shared__ f16 Qs[128 * 136];
    __shared__ f16 Ks[64 * 136];
    const int tid  = threadIdx.x;
    const int gr0  = blockIdx.x * 128;
    const int col0 = blockIdx.y * 64;
    const int b    = gr0 >> 11;
    const size_t qrow0 = (size_t)b * L_ + S_ + (gr0 & 2047);
    const size_t krow0 = (size_t)b * L_ + col0;

    #pragma unroll
    for (int i = 0; i < 8; ++i) {
        int g = tid + 256 * i;                 // 128 rows x 16 uint4
        int r = g >> 4, c = g & 15;
        *(uint4*)(Qs + r * 136 + c * 8) = *(const uint4*)(qsp + (qrow0 + r) * 128 + c * 8);
    }
    #pragma unroll
    for (int i = 0; i < 4; ++i) {
        int g = tid + 256 * i;                 // 64 rows x 16 uint4
        int r = g >> 4, c = g & 15;
        *(uint4*)(Ks + r * 136 + c * 8) = *(const uint4*)(ksp + (krow0 + r) * 128 + c * 8);
    }
    __syncthreads();

    const int w = tid >> 6, lane = tid & 63;
    const int cl = lane & 15, quad = lane >> 4;

    f32x4 acc[2][4];
    #pragma unroll
    for (int i = 0; i < 2; ++i)
        #pragma unroll
        for (int j = 0; j < 4; ++j) acc[i][j] = 0.f;

    #pragma unroll
    for (int h = 0; h < 2; ++h) {
        half8 ah[2], al[2], bh[4], bl[4];
        #pragma unroll
        for (int rs = 0; rs < 2; ++rs) {
            const f16* base = Qs + (32 * w + 16 * rs + cl) * 136 + h * 32 + quad * 8;
            ah[rs] = *(const half8*)(base);
            al[rs] = *(const half8*)(base + 64);
        }
        #pragma unroll
        for (int c = 0; c < 4; ++c) {
            const f16* base = Ks + (16 * c + cl) * 136 + h * 32 + quad * 8;
            bh[c] = *(const half8*)(base);
            bl[c] = *(const half8*)(base + 64);
        }
        #pragma unroll
        for (int rs = 0; rs < 2; ++rs)
            #pragma unroll
            for (int c = 0; c < 4; ++c) {
                acc[rs][c] = __builtin_amdgcn_mfma_f32_16x16x32_f16(ah[rs], bh[c], acc[rs][c], 0, 0, 0);
                acc[rs][c] = __builtin_amdgcn_mfma_f32_16x16x32_f16(ah[rs], bl[c], acc[rs][c], 0, 0, 0);
                acc[rs][c] = __builtin_amdgcn_mfma_f32_16x16x32_f16(al[rs], bh[c], acc[rs][c], 0, 0, 0);
            }
    }

    #pragma unroll
    for (int rs = 0; rs < 2; ++rs)
        #pragma unroll
        for (int c = 0; c < 4; ++c)
            #pragma unroll
            for (int r = 0; r < 4; ++r) {
                int mrow = gr0 + 32 * w + 16 * rs + quad * 4 + r;
                int n    = col0 + 16 * c + cl;
                D[(size_t)mrow * NCOLS + n] = acc[rs][c][r];
            }
}

// ---------------------------------------------------------------------------
// k_scan: fused cope + gates -> suffix scan -> CoPE bias -> softmax.
// Reads fp32 D row, writes fp16 P in place (head of the row, pitch PROWS).
// grid 8192 x 256.
// ---------------------------------------------------------------------------
__global__ __launch_bounds__(256) void k_scan(
    const float* __restrict__ qf, const float* __restrict__ cope,
    float* __restrict__ D)
{
    __shared__ float qv[DK];
    __shared__ float li[128];
    __shared__ float red[256];
    __shared__ float wtot[4];
    const int tid = threadIdx.x;
    const int gr  = blockIdx.x;
    const int b   = gr >> 11;
    const int q   = gr & 2047;
    const size_t grow = (size_t)b * L_ + S_ + q;

    if (tid < 16) ((float4*)qv)[tid] = ((const float4*)qf)[grow * 16 + tid];
    __syncthreads();
    if (tid < 128) {
        float a = 0.f;
        #pragma unroll
        for (int d = 0; d < DK; ++d) a += qv[d] * cope[d * S_ + tid];
        li[tid] = a;
    }

    const float* Dr = D + (size_t)gr * NCOLS;
    const int j0 = tid * 8;
    float dot[8], gte[8];
    *(float4*)&dot[0] = *(const float4*)(Dr + 128 + j0);
    *(float4*)&dot[4] = *(const float4*)(Dr + 128 + j0 + 4);
    float sv = (tid < 128) ? Dr[tid] * SCALE : NEGINF;

    float csum = 0.f;
    #pragma unroll
    for (int jj = 0; jj < 8; ++jj) {
        gte[jj] = 1.f / (1.f + __expf(-dot[jj]));
        csum += gte[jj];
    }
    const int lane = tid & 63, wid = tid >> 6;
    float inc = csum;
    #pragma unroll
    for (int off = 1; off < 64; off <<= 1) {
        float u = __shfl_down(inc, off, 64);
        if (lane + off < 64) inc += u;
    }
    if (lane == 0) wtot[wid] = inc;
    __syncthreads();
    float wsuf = 0.f;
    #pragma unroll
    for (int w = 0; w < 4; ++w) if (w > wid) wsuf += wtot[w];
    float run = inc - csum + wsuf;           // exclusive suffix across block

    float p8[8];
    #pragma unroll
    for (int jj = 7; jj >= 0; --jj) {
        run += gte[jj];
        float pos = fminf(run, (float)(S_ - 1));
        float pfl = floorf(pos);
        int ic  = (int)ceilf(pos);
        int ifl = (int)pfl;
        float w = pos - pfl;
        float bias = li[ic] * w + li[ifl] * (1.f - w);
        p8[jj] = (j0 + jj <= q) ? dot[jj] * SCALE + bias : NEGINF;
    }

    float mx = sv;
    #pragma unroll
    for (int jj = 0; jj < 8; ++jj) mx = fmaxf(mx, p8[jj]);
    red[tid] = mx;
    __syncthreads();
    for (int off = 128; off > 0; off >>= 1) {
        if (tid < off) red[tid] = fmaxf(red[tid], red[tid + off]);
        __syncthreads();
    }
    mx = red[0];
    __syncthreads();

    float lsum = 0.f;
    float e8[8];
    #pragma unroll
    for (int jj = 0; jj < 8; ++jj) {
        e8[jj] = __expf(p8[jj] - mx);
        lsum += e8[jj];
    }
    float es = 0.f;
    if (tid < 128) { es = __expf(sv - mx); lsum += es; }
    red[tid] = lsum;
    __syncthreads();
    for (int off = 128; off > 0; off >>= 1) {
        if (tid < off) red[tid] += red[tid + off];
        __syncthreads();
    }
    float inv = 1.f / red[0];

    f16* pb = (f16*)D + (size_t)gr * PROWS;
    const int qlim = (q & ~63) + 64;         // mid cols written (matches pv cmax)
    if (j0 < qlim) {
        U4 o;
        #pragma unroll
        for (int jj = 0; jj < 8; ++jj) o.h[jj] = (f16)(e8[jj] * inv);
        *(uint4*)(pb + 128 + j0) = o.u;
    }
    if (tid < 128) pb[tid] = (f16)(es * inv);
}

// ---------------------------------------------------------------------------
// k_pv: O = P(fp16) @ V(fp16 transposed) via MFMA, 4-way K-split.
// grid (128, 4) x 256. Tile 64 q-rows x 64 dims, chunk 64 keys.
// ---------------------------------------------------------------------------
__global__ __launch_bounds__(256) void k_pv(
    const f16* __restrict__ Pb, const f16* __restrict__ vhT,
    float* __restrict__ Opart)
{
    __shared__ f16 Ps[64 * 72];   // [q-row][key]
    __shared__ f16 Vt[64 * 72];   // [dim][key]
    const int tid = threadIdx.x;
    const int gr0 = blockIdx.x * 64;
    const int ks  = blockIdx.y;
    const int b   = gr0 >> 11, q0 = gr0 & 2047;
    const int cmax  = (191 + q0) >> 6;
    const int c_beg = ks * 9;
    int c_end = c_beg + 9;
    if (c_end > 34) c_end = 34;
    if (c_end > cmax + 1) c_end = cmax + 1;

    const int w = tid >> 6, lane = tid & 63;
    const int cl = lane & 15, quad = lane >> 4;
    f32x4 acc[4];
    #pragma unroll
    for (int c = 0; c < 4; ++c) acc[c] = 0.f;

    for (int ch = c_beg; ch < c_end; ++ch) {
        __syncthreads();
        #pragma unroll
        for (int i = 0; i < 2; ++i) {
            int g = tid + 256 * i;       // 64 rows x 8 uint4
            int r = g >> 3, c = g & 7;
            *(uint4*)(Ps + r * 72 + c * 8) =
                *(const uint4*)(Pb + (size_t)(gr0 + r) * PROWS + ch * 64 + c * 8);
            *(uint4*)(Vt + r * 72 + c * 8) =
                *(const uint4*)(vhT + (size_t)(b * 64 + r) * L_ + ch * 64 + c * 8);
        }
        __syncthreads();
        #pragma unroll
        for (int h = 0; h < 2; ++h) {
            half8 a = *(const half8*)(Ps + (16 * w + cl) * 72 + h * 32 + quad * 8);
            #pragma unroll
            for (int c = 0; c < 4; ++c) {
                half8 bv = *(const half8*)(Vt + (16 * c + cl) * 72 + h * 32 + quad * 8);
                acc[c] = __builtin_amdgcn_mfma_f32_16x16x32_f16(a, bv, acc[c], 0, 0, 0);
            }
        }
    }
    #pragma unroll
    for (int c = 0; c < 4; ++c)
        #pragma unroll
        for (int r = 0; r < 4; ++r) {
            int mrow = gr0 + 16 * w + quad * 4 + r;
            int n    = 16 * c + cl;
            Opart[((size_t)ks * NMID + mrow) * DK + n] = acc[c][r];
        }
}

// ---------------------------------------------------------------------------
// k_merge: out(mid rows) = sum of 4 partials. grid 2048 x 256.
// ---------------------------------------------------------------------------
__global__ __launch_bounds__(256) void k_merge(
    const float* __restrict__ Opart, float* __restrict__ out)
{
    const int e  = blockIdx.x * 256 + threadIdx.x;
    const int gr = e >> 6, c = e & 63;
    const int b  = gr >> 11, q = gr & 2047;
    const int NP = NMID * DK;
    float s = Opart[e] + Opart[e + NP] + Opart[e + 2 * NP] + Opart[e + 3 * NP];
    out[((size_t)b * L_ + S_ + q) * DK + c] = s;
}

// ---------------------------------------------------------------------------
// k_dots_edge: De[er][col] = q_edge[er] . k[col]. grid (8,18) x 256. (fp32)
// ---------------------------------------------------------------------------
__global__ __launch_bounds__(256) void k_dots_edge(
    const float* __restrict__ qf, const float* __restrict__ kf,
    float* __restrict__ De)
{
    const int bx   = blockIdx.x;
    const int b    = bx >> 1;
    const int half = bx & 1;
    const int col0 = blockIdx.y * 128;
    if (half == 0 && col0 > 127) return;

    __shared__ float Qs[128 * 68];
    __shared__ float Kt[64 * 136];
    const int tid = threadIdx.x;
    const int er0 = bx * 128;
    const size_t qrow0 = (size_t)b * L_ + (half ? 2176 : 0);
    const size_t krow0 = (size_t)b * L_ + col0;

    #pragma unroll
    for (int i = 0; i < 8; ++i) {
        int g = tid + 256 * i;
        int r = g >> 4, f = g & 15;
        *(float4*)(Qs + r * 68 + f * 4) = ((const float4*)qf)[(qrow0 + r) * 16 + f];
    }
    #pragma unroll
    for (int i = 0; i < 8; ++i) {
        int g = tid + 256 * i;
        int j = g >> 4, f = g & 15;
        float4 kv = ((const float4*)kf)[(krow0 + j) * 16 + f];
        Kt[(f * 4 + 0) * 136 + j] = kv.x;
        Kt[(f * 4 + 1) * 136 + j] = kv.y;
        Kt[(f * 4 + 2) * 136 + j] = kv.z;
        Kt[(f * 4 + 3) * 136 + j] = kv.w;
    }
    __syncthreads();

    const int c8 = tid & 15, r8 = tid >> 4;
    float acc[8][8] = {};
    for (int d0 = 0; d0 < 64; d0 += 4) {
        float4 a[8];
        #pragma unroll
        for (int i = 0; i < 8; ++i)
            a[i] = *(const float4*)(Qs + (r8 * 8 + i) * 68 + d0);
        #pragma unroll
        for (int dd = 0; dd < 4; ++dd) {
            float4 k0 = *(const float4*)(Kt + (d0 + dd) * 136 + c8 * 8);
            float4 k1 = *(const float4*)(Kt + (d0 + dd) * 136 + c8 * 8 + 4);
            #pragma unroll
            for (int i = 0; i < 8; ++i) {
                float av = (dd == 0) ? a[i].x : (dd == 1) ? a[i].y : (dd == 2) ? a[i].z : a[i].w;
                acc[i][0] += av * k0.x; acc[i][1] += av * k0.y;
                acc[i][2] += av * k0.z; acc[i][3] += av * k0.w;
                acc[i][4] += av * k1.x; acc[i][5] += av * k1.y;
                acc[i][6] += av * k1.z; acc[i][7] += av * k1.w;
            }
        }
    }
    #pragma unroll
    for (int i = 0; i < 8; ++i) {
        size_t o = (size_t)(er0 + r8 * 8 + i) * LE + col0 + c8 * 8;
        *(float4*)(De + o)     = make_float4(acc[i][0], acc[i][1], acc[i][2], acc[i][3]);
        *(float4*)(De + o + 4) = make_float4(acc[i][4], acc[i][5], acc[i][6], acc[i][7]);
    }
}

// ---------------------------------------------------------------------------
// k_soft_edge: row-wise causal softmax on De. grid 1024 x 256.
// ---------------------------------------------------------------------------
__global__ __launch_bounds__(256) void k_soft_edge(float* __restrict__ De)
{
    __shared__ float red[256];
    const int tid = threadIdx.x;
    const int er  = blockIdx.x;
    const int r   = er & 255;
    const int Q   = (r < 128) ? r : (2048 + r);
    const size_t rowoff = (size_t)er * LE;

    float v[9];
    #pragma unroll
    for (int i = 0; i < 9; ++i) {
        int j = tid + 256 * i;
        float d = De[rowoff + j];
        v[i] = (j <= Q) ? d * SCALE : NEGINF;
    }
    float mx = v[0];
    #pragma unroll
    for (int i = 1; i < 9; ++i) mx = fmaxf(mx, v[i]);
    red[tid] = mx;
    __syncthreads();
    for (int off = 128; off > 0; off >>= 1) {
        if (tid < off) red[tid] = fmaxf(red[tid], red[tid + off]);
        __syncthreads();
    }
    mx = red[0];
    __syncthreads();

    float lsum = 0.f;
    #pragma unroll
    for (int i = 0; i < 9; ++i) {
        v[i] = __expf(v[i] - mx);
        lsum += v[i];
    }
    red[tid] = lsum;
    __syncthreads();
    for (int off = 128; off > 0; off >>= 1) {
        if (tid < off) red[tid] += red[tid + off];
        __syncthreads();
    }
    float inv = 1.f / red[0];
    #pragma unroll
    for (int i = 0; i < 9; ++i)
        De[rowoff + tid + 256 * i] = v[i] * inv;
}

// ---------------------------------------------------------------------------
// k_pv_edge: partial Oe = Pe @ V, 4-way K-split over 36 chunks. grid (32,4).
// ---------------------------------------------------------------------------
__global__ __launch_bounds__(256) void k_pv_edge(
    const float* __restrict__ De, const float* __restrict__ vf,
    float* __restrict__ Oe)
{
    __shared__ float Ps[32 * 68];
    __shared__ float Vs[64 * 68];
    const int tid = threadIdx.x;
    const int er0 = blockIdx.x * 32;
    const int ks  = blockIdx.y;
    const int b   = er0 >> 8, r0 = er0 & 255;
    const int Qmax = (r0 < 128) ? (r0 + 31) : (2048 + r0 + 31);
    const int cmax = Qmax >> 6;
    const int c_beg = ks * 9;
    int c_end = c_beg + 9;
    if (c_end > 36) c_end = 36;
    if (c_end > cmax + 1) c_end = cmax + 1;

    const int c4 = tid & 15, rg = tid >> 4;
    float acc[2][4] = {};

    for (int ch = c_beg; ch < c_end; ++ch) {
        __syncthreads();
        #pragma unroll
        for (int i = 0; i < 2; ++i) {
            int g = tid + 256 * i;
            int r = g >> 4, f = g & 15;
            *(float4*)(Ps + r * 68 + f * 4) =
                *(const float4*)(De + (size_t)(er0 + r) * LE + ch * 64 + f * 4);
        }
        #pragma unroll
        for (int i = 0; i < 4; ++i) {
            int g = tid + 256 * i;
            int j = g >> 4, f = g & 15;
            *(float4*)(Vs + j * 68 + f * 4) =
                *(const float4*)(vf + (size_t)(b * L_ + ch * 64 + j) * DK + f * 4);
        }
        __syncthreads();
        #pragma unroll 4
        for (int j = 0; j < 64; ++j) {
            float4 vv = *(const float4*)(Vs + j * 68 + c4 * 4);
            float p0 = Ps[(rg * 2 + 0) * 68 + j];
            float p1 = Ps[(rg * 2 + 1) * 68 + j];
            acc[0][0] += p0 * vv.x; acc[0][1] += p0 * vv.y;
            acc[0][2] += p0 * vv.z; acc[0][3] += p0 * vv.w;
            acc[1][0] += p1 * vv.x; acc[1][1] += p1 * vv.y;
            acc[1][2] += p1 * vv.z; acc[1][3] += p1 * vv.w;
        }
    }
    #pragma unroll
    for (int i = 0; i < 2; ++i)
        *(float4*)(Oe + ((size_t)ks * NEDGE + er0 + rg * 2 + i) * DK + c4 * 4) =
            make_float4(acc[i][0], acc[i][1], acc[i][2], acc[i][3]);
}

// ---------------------------------------------------------------------------
// k_merge_edge: out(edge rows) = sum of 4 partials. grid 256 x 256.
// ---------------------------------------------------------------------------
__global__ __launch_bounds__(256) void k_merge_edge(
    const float* __restrict__ Oe, float* __restrict__ out)
{
    const int e  = blockIdx.x * 256 + threadIdx.x;
    const int er = e >> 6, c = e & 63;
    const int b  = er >> 8, r = er & 255;
    const int gQ = (r < 128) ? r : (2048 + r);
    const int NP = NEDGE * DK;
    float s = Oe[e] + Oe[e + NP] + Oe[e + 2 * NP] + Oe[e + 3 * NP];
    out[((size_t)b * L_ + gQ) * DK + c] = s;
}

// ---------------------------------------------------------------------------
extern "C" void kernel_launch(void* const* d_in, const int* in_sizes, int n_in,
                              void* d_out, int out_size, void* d_ws, size_t ws_size,
                              hipStream_t stream)
{
    const float* x    = (const float*)d_in[0];
    const float* Wq   = (const float*)d_in[1];
    const float* Wk   = (const float*)d_in[2];
    const float* Wv   = (const float*)d_in[3];
    const float* Wqs  = (const float*)d_in[4];
    const float* Wks  = (const float*)d_in[5];
    const float* Wvs  = (const float*)d_in[6];
    const float* Wqe  = (const float*)d_in[7];
    const float* Wke  = (const float*)d_in[8];
    const float* Wve  = (const float*)d_in[9];
    const float* g0   = (const float*)d_in[10];
    const float* b0   = (const float*)d_in[11];
    const float* gs   = (const float*)d_in[12];
    const float* bs   = (const float*)d_in[13];
    const float* ge   = (const float*)d_in[14];
    const float* be   = (const float*)d_in[15];
    const float* cope = (const float*)d_in[16];

    const size_t NR = (size_t)B_ * L_;               // 9216 rows
    float* ws = (float*)d_ws;
    float* qf    = ws;                               // 9216*64 f32
    float* kf    = qf + NR * DK;
    float* vf    = kf + NR * DK;
    float* Opart = vf + NR * DK;                     // 4*8192*64 f32
    f16*   qsp   = (f16*)(Opart + (size_t)4 * NMID * DK);  // 9216*128 h (hi|lo)
    f16*   ksp   = qsp + NR * 128;
    f16*   vhT   = ksp + NR * 128;                   // 4*64*2304 h
    float* D     = (float*)(vhT + NR * DK);          // 8192*2176 f32
    // xh/xl live INSIDE D's region (dead before k_dots writes D)
    f16*   xh    = (f16*)D;                          // 9216*512 h
    f16*   xl    = xh + NR * DIN;                    // 9216*512 h
    float* De    = D;                                // edge reuses D after k_pv
    float* Oe    = Opart;                            // edge reuses Opart after k_merge
    float* out   = (float*)d_out;

    k_ln  <<<L_ * B_ / 4, 256, 0, stream>>>(x, g0, b0, gs, bs, ge, be, xh, xl);
    k_proj<<<dim3(144, 3), 256, 0, stream>>>(xh, xl, Wq, Wk, Wv, Wqs, Wks, Wvs,
                                             Wqe, Wke, Wve, qf, kf, vf,
                                             qsp, ksp, vhT);
    k_dots<<<dim3(NMID / 128, NCOLS / 64), 256, 0, stream>>>(qsp, ksp, D);
    k_scan<<<NMID, 256, 0, stream>>>(qf, cope, D);
    k_pv  <<<dim3(NMID / 64, 4), 256, 0, stream>>>((const f16*)D, vhT, Opart);
    k_merge<<<NMID * DK / 256, 256, 0, stream>>>(Opart, out);
    // edge path (reuses D's memory after k_pv, Opart after k_merge)
    k_dots_edge<<<dim3(8, 18), 256, 0, stream>>>(qf, kf, De);
    k_soft_edge<<<NEDGE, 256, 0, stream>>>(De);
    k_pv_edge<<<dim3(NEDGE / 32, 4), 256, 0, stream>>>(De, vf, Oe);
    k_merge_edge<<<NEDGE * DK / 256, 256, 0, stream>>>(Oe, out);
}